// Round 20
// baseline (268.392 us; speedup 1.0000x reference)
//
#include <hip/hip_runtime.h>
#include <hip/hip_bf16.h>

// Problem constants (B=4, L=1024, D=1024, H=16, Dh=64, MAX_LEN=150)
#define BB 4
#define LL 1024
#define DD 1024
#define HH 16
#define DH 64
#define NPOS 301      // 2*MAX_LEN+1
#define MAXL 150
#define NEG_INF -1e30f

typedef __attribute__((ext_vector_type(4))) float f32x4;
typedef __attribute__((ext_vector_type(8))) short short8;

__device__ inline unsigned short f2b(float x) {
    __hip_bfloat16 h = __float2bfloat16(x);
    return *reinterpret_cast<unsigned short*>(&h);
}
__device__ inline unsigned pack2(float a, float b) {
    return (unsigned)f2b(a) | ((unsigned)f2b(b) << 16);
}
__device__ inline float b2f(unsigned short u) {
    return __uint_as_float((unsigned)u << 16);
}

// Load 8 contiguous elements as bf16x8, converting from f32 when F32=true.
template <bool F32>
__device__ inline short8 ld8(const void* p, size_t off) {
    if constexpr (F32) {
        const float* q = (const float*)p + off;
        float4 a = *reinterpret_cast<const float4*>(q);
        float4 b = *reinterpret_cast<const float4*>(q + 4);
        short8 r;
        r[0] = (short)f2b(a.x); r[1] = (short)f2b(a.y);
        r[2] = (short)f2b(a.z); r[3] = (short)f2b(a.w);
        r[4] = (short)f2b(b.x); r[5] = (short)f2b(b.y);
        r[6] = (short)f2b(b.z); r[7] = (short)f2b(b.w);
        return r;
    } else {
        return *reinterpret_cast<const short8*>((const unsigned short*)p + off);
    }
}

// ---------------------------------------------------------------------------
// Mask bit-pack: mask[b][q][k] (nonzero = masked) -> one bit per element.
// ---------------------------------------------------------------------------
__global__ __launch_bounds__(256) void pack_mask(const int* __restrict__ mask,
                                                 unsigned long long* __restrict__ bits)
{
    const int wid = (blockIdx.x * 256 + threadIdx.x) >> 6;   // global wave id
    const int lane = threadIdx.x & 63;
    const int v = mask[(size_t)wid * 64 + lane];
    const unsigned long long b = __ballot(v != 0);
    if (lane == 0) bits[wid] = b;
}

// ---------------------------------------------------------------------------
// bf16 MFMA GEMM core (128 x 64 tile) — r14-validated config for the final
// projection (BKT=32) and the qpos table (BKT=64, single K-step at K=64).
// EPI 0: f32 [M][N]; EPI 1: bf16 [bh][l][dh]; EPI 2: bf16 [bh][dh][l];
// EPI 3: bf16 plain [M][N] (GN guards N).
// ---------------------------------------------------------------------------
template <int BKT, bool GN, bool AF32, bool WF32>
__device__ __forceinline__ void gemm_body(
    const void* __restrict__ A, const void* __restrict__ W,
    const float* __restrict__ bias, void* __restrict__ Cout,
    int M, int N, int K, float oscale, int epi,
    int m0, int n0, unsigned short* As, unsigned short* Bs)
{
    constexpr int PAD = BKT + 8;
    const int tid = threadIdx.x;
    const int w = tid >> 6, lane = tid & 63;
    const int wr = w >> 1, wc = w & 1;
    const int g = lane >> 4, fr = lane & 15;

    f32x4 acc[4][2];
#pragma unroll
    for (int i = 0; i < 4; ++i)
#pragma unroll
        for (int j = 0; j < 2; ++j) acc[i][j] = (f32x4){0.f, 0.f, 0.f, 0.f};

    const int arow0 = tid >> 2, agg = (tid & 3) * 8;
    for (int k0 = 0; k0 < K; k0 += BKT) {
        if constexpr (BKT == 32) {
            short8 v0 = ld8<AF32>(A, (size_t)(m0 + arow0) * K + k0 + agg);
            short8 v1 = ld8<AF32>(A, (size_t)(m0 + arow0 + 64) * K + k0 + agg);
            int nr = n0 + arow0;
            if (GN && nr >= N) nr = N - 1;
            short8 bv = ld8<WF32>(W, (size_t)nr * K + k0 + agg);
            *reinterpret_cast<short8*>(&As[arow0 * PAD + agg]) = v0;
            *reinterpret_cast<short8*>(&As[(arow0 + 64) * PAD + agg]) = v1;
            *reinterpret_cast<short8*>(&Bs[arow0 * PAD + agg]) = bv;
        } else {
            short8 a00 = ld8<AF32>(A, (size_t)(m0 + arow0) * K + k0 + agg);
            short8 a01 = ld8<AF32>(A, (size_t)(m0 + arow0) * K + k0 + agg + 32);
            short8 a10 = ld8<AF32>(A, (size_t)(m0 + arow0 + 64) * K + k0 + agg);
            short8 a11 = ld8<AF32>(A, (size_t)(m0 + arow0 + 64) * K + k0 + agg + 32);
            int nr = n0 + arow0;
            if (GN && nr >= N) nr = N - 1;
            short8 b0 = ld8<WF32>(W, (size_t)nr * K + k0 + agg);
            short8 b1 = ld8<WF32>(W, (size_t)nr * K + k0 + agg + 32);
            *reinterpret_cast<short8*>(&As[arow0 * PAD + agg]) = a00;
            *reinterpret_cast<short8*>(&As[arow0 * PAD + agg + 32]) = a01;
            *reinterpret_cast<short8*>(&As[(arow0 + 64) * PAD + agg]) = a10;
            *reinterpret_cast<short8*>(&As[(arow0 + 64) * PAD + agg + 32]) = a11;
            *reinterpret_cast<short8*>(&Bs[arow0 * PAD + agg]) = b0;
            *reinterpret_cast<short8*>(&Bs[arow0 * PAD + agg + 32]) = b1;
        }
        __syncthreads();
#pragma unroll
        for (int kk = 0; kk < BKT / 32; ++kk) {
            short8 af[4], bf[2];
#pragma unroll
            for (int i = 0; i < 4; ++i)
                af[i] = *reinterpret_cast<const short8*>(
                    &As[(wr * 64 + i * 16 + fr) * PAD + kk * 32 + g * 8]);
#pragma unroll
            for (int j = 0; j < 2; ++j)
                bf[j] = *reinterpret_cast<const short8*>(
                    &Bs[(wc * 32 + j * 16 + fr) * PAD + kk * 32 + g * 8]);
#pragma unroll
            for (int i = 0; i < 4; ++i)
#pragma unroll
                for (int j = 0; j < 2; ++j)
                    acc[i][j] = __builtin_amdgcn_mfma_f32_16x16x32_bf16(
                        af[i], bf[j], acc[i][j], 0, 0, 0);
        }
        __syncthreads();
    }

#pragma unroll
    for (int i = 0; i < 4; ++i) {
#pragma unroll
        for (int j = 0; j < 2; ++j) {
#pragma unroll
            for (int r = 0; r < 4; ++r) {
                const int row = m0 + wr * 64 + i * 16 + g * 4 + r;
                const int col = n0 + wc * 32 + j * 16 + fr;
                if (GN && col >= N) continue;
                const float val = (acc[i][j][r] + (bias ? bias[col] : 0.f)) * oscale;
                if (epi == 0) {
                    ((float*)Cout)[(size_t)row * N + col] = val;
                } else if (epi == 1) {
                    const int b = row >> 10, l = row & 1023, hh = col >> 6, dh = col & 63;
                    ((unsigned short*)Cout)[(((size_t)(b * HH + hh)) * LL + l) * DH + dh] = f2b(val);
                } else if (epi == 2) {
                    const int b = row >> 10, l = row & 1023, hh = col >> 6, dh = col & 63;
                    ((unsigned short*)Cout)[(((size_t)(b * HH + hh)) * DH + dh) * LL + l] = f2b(val);
                } else {
                    ((unsigned short*)Cout)[(size_t)row * N + col] = f2b(val);
                }
            }
        }
    }
}

// Single-matrix GEMM (qpos table at BKT=64, final projection at BKT=32)
template <int EPI, bool GN, bool AF32, bool WF32, int BKT>
__global__ __launch_bounds__(256) void gemm_mfma(
    const void* __restrict__ A, const void* __restrict__ W,
    const float* __restrict__ bias, void* __restrict__ Cout,
    int M, int N, int K, float oscale)
{
    __shared__ alignas(16) unsigned short As[128 * (BKT + 8)];
    __shared__ alignas(16) unsigned short Bs[64 * (BKT + 8)];
    gemm_body<BKT, GN, AF32, WF32>(A, W, bias, Cout, M, N, K, oscale, EPI,
                                   blockIdx.y * 128, blockIdx.x * 64, As, Bs);
}

// ---------------------------------------------------------------------------
// 128 x 128 tile GEMM body (validated r19: 16 MFMA per 8 ds_read per K-step;
// viable because the z-merged launch gives 768 blocks = 3/CU co-resident).
// ---------------------------------------------------------------------------
template <bool AF32, bool WF32>
__device__ __forceinline__ void gemm_body128(
    const void* __restrict__ A, const void* __restrict__ W,
    const float* __restrict__ bias, void* __restrict__ Cout,
    int M, int N, int K, float oscale, int epi,
    int m0, int n0, unsigned short* As, unsigned short* Bs)
{
    const int tid = threadIdx.x;
    const int w = tid >> 6, lane = tid & 63;
    const int wr = w >> 1, wc = w & 1;
    const int g = lane >> 4, fr = lane & 15;

    f32x4 acc[4][4];
#pragma unroll
    for (int i = 0; i < 4; ++i)
#pragma unroll
        for (int j = 0; j < 4; ++j) acc[i][j] = (f32x4){0.f, 0.f, 0.f, 0.f};

    const int arow0 = tid >> 2, agg = (tid & 3) * 8;
    for (int k0 = 0; k0 < K; k0 += 32) {
        {
            short8 a0 = ld8<AF32>(A, (size_t)(m0 + arow0) * K + k0 + agg);
            short8 a1 = ld8<AF32>(A, (size_t)(m0 + arow0 + 64) * K + k0 + agg);
            short8 b0 = ld8<WF32>(W, (size_t)(n0 + arow0) * K + k0 + agg);
            short8 b1 = ld8<WF32>(W, (size_t)(n0 + arow0 + 64) * K + k0 + agg);
            *reinterpret_cast<short8*>(&As[arow0 * 40 + agg]) = a0;
            *reinterpret_cast<short8*>(&As[(arow0 + 64) * 40 + agg]) = a1;
            *reinterpret_cast<short8*>(&Bs[arow0 * 40 + agg]) = b0;
            *reinterpret_cast<short8*>(&Bs[(arow0 + 64) * 40 + agg]) = b1;
        }
        __syncthreads();
        short8 af[4], bf[4];
#pragma unroll
        for (int i = 0; i < 4; ++i)
            af[i] = *reinterpret_cast<const short8*>(
                &As[(wr * 64 + i * 16 + fr) * 40 + g * 8]);
#pragma unroll
        for (int j = 0; j < 4; ++j)
            bf[j] = *reinterpret_cast<const short8*>(
                &Bs[(wc * 64 + j * 16 + fr) * 40 + g * 8]);
#pragma unroll
        for (int i = 0; i < 4; ++i)
#pragma unroll
            for (int j = 0; j < 4; ++j)
                acc[i][j] = __builtin_amdgcn_mfma_f32_16x16x32_bf16(
                    af[i], bf[j], acc[i][j], 0, 0, 0);
        __syncthreads();
    }

#pragma unroll
    for (int i = 0; i < 4; ++i) {
#pragma unroll
        for (int j = 0; j < 4; ++j) {
#pragma unroll
            for (int r = 0; r < 4; ++r) {
                const int row = m0 + wr * 64 + i * 16 + g * 4 + r;
                const int col = n0 + wc * 64 + j * 16 + fr;
                const float val = (acc[i][j][r] + (bias ? bias[col] : 0.f)) * oscale;
                if (epi == 1) {
                    const int b = row >> 10, l = row & 1023, hh = col >> 6, dh = col & 63;
                    ((unsigned short*)Cout)[(((size_t)(b * HH + hh)) * LL + l) * DH + dh] = f2b(val);
                } else {
                    const int b = row >> 10, l = row & 1023, hh = col >> 6, dh = col & 63;
                    ((unsigned short*)Cout)[(((size_t)(b * HH + hh)) * DH + dh) * LL + l] = f2b(val);
                }
            }
        }
    }
}

// Merged Q/K/V projection, 128x128 tile (z selects matrix); 768 blocks.
__global__ __launch_bounds__(256) void gemm_qkv(
    const float* __restrict__ Q, const float* __restrict__ K,
    const float* __restrict__ V,
    const float* __restrict__ Wq, const float* __restrict__ Wk,
    const float* __restrict__ Wv,
    const float* __restrict__ bq, const float* __restrict__ bk,
    const float* __restrict__ bv,
    unsigned short* __restrict__ qbf, unsigned short* __restrict__ kbf,
    unsigned short* __restrict__ vT)
{
    __shared__ alignas(16) unsigned short As[128 * 40];
    __shared__ alignas(16) unsigned short Bs[128 * 40];
    const int z = blockIdx.z;
    const float* A = (z == 0) ? Q : (z == 1) ? K : V;
    const float* W = (z == 0) ? Wq : (z == 1) ? Wk : Wv;
    const float* bias = (z == 0) ? bq : (z == 1) ? bk : bv;
    void* Cout = (z == 0) ? (void*)qbf : (z == 1) ? (void*)kbf : (void*)vT;
    const int epi = (z == 2) ? 2 : 1;
    const float oscale = (z == 0) ? 0.125f : 1.0f;
    gemm_body128<true, true>(A, W, bias, Cout, BB * LL, DD, DD, oscale, epi,
                             blockIdx.y * 128, blockIdx.x * 128, As, Bs);
}

// ---------------------------------------------------------------------------
// MFMA attention — r14 structure (135 us), ROUND 20: + s_setprio(1) around
// the QK and PV MFMA clusters (T5). The main loop has NO barriers, so the 4
// waves/block free-run at different phases (m191's regime: setprio +4-7% for
// independent attn waves; the GEMM-lockstep null of m190 doesn't apply).
// Math unchanged -> output bit-identical.
// ---------------------------------------------------------------------------
__global__ __launch_bounds__(256) void attn_mfma(
    const unsigned short* __restrict__ qbf,   // [bh][l][dh] bf16 (scaled 1/8)
    const unsigned short* __restrict__ kbf,   // [bh][l][dh] bf16
    const unsigned short* __restrict__ vT,    // [bh][dh][l] bf16
    const unsigned short* __restrict__ qpos,  // [bh*L][301] bf16 (scaled 1/8)
    const unsigned long long* __restrict__ mbits, // [b][q][L/64] bit-mask
    unsigned short* __restrict__ outb)        // [b][l][D] bf16
{
    const int bh = blockIdx.x;                // fast dim -> same-bh on one XCD
    const int qblk = blockIdx.y;
    const int b = bh >> 4, h = bh & 15;
    const int tid = threadIdx.x;
    const int w = tid >> 6;                   // 0..3
    const int qh = w & 1;                     // q-group
    const int kh = w >> 1;                    // k-half
    const int lane = tid & 63;
    const int g = lane >> 4;
    const int qc = lane & 15;
    const int gq = qblk * 32 + qh * 16 + qc;
    const int ql = qh * 16 + qc;              // local q row (0..31)

    __shared__ alignas(16) unsigned char Plds[4 * 2048];
    __shared__ alignas(16) unsigned short Qp[32 * NPOS];   // 19264 B; aliased
    float* Mrg = (float*)Qp;                  // as merge buf after 2nd barrier
    unsigned char* myP = Plds + w * 2048 + qc * 128;
    const int swz = (qc & 7) << 4;

    // ---- stage qpos slab (contiguous 32*301 bf16), coalesced ----
    {
        const unsigned short* qslab = qpos + ((size_t)bh * LL + (size_t)qblk * 32) * NPOS;
        for (int i = tid; i < (32 * NPOS) / 8; i += 256)
            *reinterpret_cast<short8*>(&Qp[i * 8]) =
                *reinterpret_cast<const short8*>(qslab + (size_t)i * 8);
    }

    const unsigned short* qrow = qbf + ((size_t)bh * LL + gq) * DH;
    const short8 qf0 = *reinterpret_cast<const short8*>(qrow + g * 8);
    const short8 qf1 = *reinterpret_cast<const short8*>(qrow + g * 8 + 32);

    const unsigned short* kb0 = kbf + (size_t)bh * LL * DH;
    const unsigned short* vb0 = vT + (size_t)bh * DH * LL;
    const unsigned long long* mwp = mbits + ((size_t)b * LL + gq) * (LL / 64);
    const unsigned short* qpr = &Qp[ql * NPOS];

    float mrun = -3.0e38f, lrun = 0.f;
    f32x4 o[4];
#pragma unroll
    for (int m = 0; m < 4; ++m) o[m] = (f32x4){0.f, 0.f, 0.f, 0.f};

    __syncthreads();                          // Qp ready (read-only in loop)
    const float c_left = b2f(qpr[300]);       // rel <= -150
    const float c_right = b2f(qpr[299]);      // rel >= +150

    // 8 tiles per wave, interleaved across k-halves
    for (int it = 0; it < 8; ++it) {
        const int kt = kh * 64 + it * 128;

        // ---- S^T = K . Q^T (priority-boosted MFMA cluster) ----
        f32x4 s[4];
#pragma unroll
        for (int m = 0; m < 4; ++m) s[m] = (f32x4){0.f, 0.f, 0.f, 0.f};
        __builtin_amdgcn_s_setprio(1);
#pragma unroll
        for (int m = 0; m < 4; ++m) {
            const unsigned short* krow = kb0 + (size_t)(kt + m * 16 + qc) * DH + g * 8;
            short8 a0 = *reinterpret_cast<const short8*>(krow);
            short8 a1 = *reinterpret_cast<const short8*>(krow + 32);
            s[m] = __builtin_amdgcn_mfma_f32_16x16x32_bf16(a0, qf0, s[m], 0, 0, 0);
            s[m] = __builtin_amdgcn_mfma_f32_16x16x32_bf16(a1, qf1, s[m], 0, 0, 0);
        }
        __builtin_amdgcn_s_setprio(0);

        // ---- scores in place: banded qpos (LDS) + bit-mask ----
        const unsigned long long mw = mwp[kt >> 6];
        float tmax = -3.0e38f;
#pragma unroll
        for (int m = 0; m < 4; ++m) {
            const int kb = kt + m * 16 + g * 4;
            const unsigned msub = (unsigned)(mw >> (m * 16 + g * 4)) & 0xFu;
            const int p0 = kb - gq + 149;     // unclipped idx of r=0
            float rp0, rp1, rp2, rp3;
            if (p0 > 299) {                   // whole run right-saturated
                rp0 = rp1 = rp2 = rp3 = c_right;
            } else if (p0 < -3) {             // whole run left-saturated
                rp0 = rp1 = rp2 = rp3 = c_left;
            } else if (p0 >= 0 && p0 <= 296) { // strictly in band (LDS reads)
                rp0 = b2f(qpr[p0]);     rp1 = b2f(qpr[p0 + 1]);
                rp2 = b2f(qpr[p0 + 2]); rp3 = b2f(qpr[p0 + 3]);
            } else {                          // straddling band edge (rare)
                int i0 = p0 < 0 ? 300 : p0;
                int i1 = p0 + 1 < 0 ? 300 : (p0 + 1 > 299 ? 299 : p0 + 1);
                int i2 = p0 + 2 < 0 ? 300 : (p0 + 2 > 299 ? 299 : p0 + 2);
                int i3 = p0 + 3 > 299 ? 299 : p0 + 3;
                rp0 = b2f(qpr[i0]); rp1 = b2f(qpr[i1]);
                rp2 = b2f(qpr[i2]); rp3 = b2f(qpr[i3]);
            }
#pragma unroll
            for (int r = 0; r < 4; ++r) {
                const float rp = (r == 0 ? rp0 : r == 1 ? rp1 : r == 2 ? rp2 : rp3);
                float x = s[m][r] + rp;       // both pre-scaled by 1/8
                x = (msub >> r) & 1 ? NEG_INF : x;
                s[m][r] = x;
                tmax = fmaxf(tmax, x);
            }
        }

        // ---- online softmax (in-register, in-place exp) ----
        tmax = fmaxf(tmax, __shfl_xor(tmax, 16));
        tmax = fmaxf(tmax, __shfl_xor(tmax, 32));
        const float nm = fmaxf(mrun, tmax);
        const float al = __expf(mrun - nm);
        mrun = nm;
        float ls = 0.f;
#pragma unroll
        for (int m = 0; m < 4; ++m)
#pragma unroll
            for (int r = 0; r < 4; ++r) {
                const float p = __expf(s[m][r] - nm);
                s[m][r] = p;
                ls += p;
            }
        ls += __shfl_xor(ls, 16);
        ls += __shfl_xor(ls, 32);
        lrun = lrun * al + ls;
#pragma unroll
        for (int m = 0; m < 4; ++m) o[m] *= al;

        // ---- P -> bf16 -> private LDS (swizzled), re-read as B-frags ----
#pragma unroll
        for (int m = 0; m < 4; ++m) {
            *reinterpret_cast<unsigned*>(myP + ((32 * m + 8 * g) ^ swz)) = pack2(s[m][0], s[m][1]);
            *reinterpret_cast<unsigned*>(myP + ((32 * m + 8 * g + 4) ^ swz)) = pack2(s[m][2], s[m][3]);
        }
        const short8 pf0 = *reinterpret_cast<const short8*>(myP + ((16 * g) ^ swz));
        const short8 pf1 = *reinterpret_cast<const short8*>(myP + ((64 + 16 * g) ^ swz));

        // ---- O^T += V^T . P^T (priority-boosted MFMA cluster) ----
        __builtin_amdgcn_s_setprio(1);
#pragma unroll
        for (int m = 0; m < 4; ++m) {
            const unsigned short* vrow = vb0 + (size_t)(m * 16 + qc) * LL + kt + g * 8;
            short8 va0 = *reinterpret_cast<const short8*>(vrow);
            short8 va1 = *reinterpret_cast<const short8*>(vrow + 32);
            o[m] = __builtin_amdgcn_mfma_f32_16x16x32_bf16(va0, pf0, o[m], 0, 0, 0);
            o[m] = __builtin_amdgcn_mfma_f32_16x16x32_bf16(va1, pf1, o[m], 0, 0, 0);
        }
        __builtin_amdgcn_s_setprio(0);
    }

    // ---- split-K merge (Mrg aliases Qp; barrier separates lifetimes) ----
    __syncthreads();                          // everyone done reading Qp
    if (kh == 1) {
        float* d = Mrg + ((size_t)qh * 64 + lane) * 18;
#pragma unroll
        for (int m = 0; m < 4; ++m)
#pragma unroll
            for (int r = 0; r < 4; ++r) d[m * 4 + r] = o[m][r];
        d[16] = mrun; d[17] = lrun;
    }
    __syncthreads();
    if (kh == 0) {
        const float* d = Mrg + ((size_t)qh * 64 + lane) * 18;
        const float m1 = d[16], l1 = d[17];
        const float M = fmaxf(mrun, m1);
        const float a0 = __expf(mrun - M), a1 = __expf(m1 - M);
        const float linv = 1.f / (lrun * a0 + l1 * a1);
        unsigned short* orow = outb + ((size_t)b * LL + gq) * DD + h * DH;
#pragma unroll
        for (int m = 0; m < 4; ++m) {
            ushort4 st;
            st.x = f2b((o[m][0] * a0 + d[m * 4 + 0] * a1) * linv);
            st.y = f2b((o[m][1] * a0 + d[m * 4 + 1] * a1) * linv);
            st.z = f2b((o[m][2] * a0 + d[m * 4 + 2] * a1) * linv);
            st.w = f2b((o[m][3] * a0 + d[m * 4 + 3] * a1) * linv);
            *reinterpret_cast<ushort4*>(orow + m * 16 + g * 4) = st;
        }
    }
}

// ---------------------------------------------------------------------------
// Inputs (dict order): 0 Q, 1 K, 2 V, 3 mask, 4 Wq, 5 bq, 6 Wk, 7 bk,
// 8 Wv, 9 bv, 10 Wo, 11 bo, 12 pos_emb.  Output: [B, L, D] float32.
// 5 dispatches. Workspace (bf16): qbf kbf vT attnb (4 x 4M) + qpos
// [65536][301] + mbits u64[65536] = ~72 MB.
// ---------------------------------------------------------------------------
extern "C" void kernel_launch(void* const* d_in, const int* in_sizes, int n_in,
                              void* d_out, int out_size, void* d_ws, size_t ws_size,
                              hipStream_t stream)
{
    const float* Q  = (const float*)d_in[0];
    const float* K  = (const float*)d_in[1];
    const float* V  = (const float*)d_in[2];
    const int* mask = (const int*)d_in[3];
    const float* Wq = (const float*)d_in[4];
    const float* bq = (const float*)d_in[5];
    const float* Wk = (const float*)d_in[6];
    const float* bk = (const float*)d_in[7];
    const float* Wv = (const float*)d_in[8];
    const float* bv = (const float*)d_in[9];
    const float* Wo = (const float*)d_in[10];
    const float* bo = (const float*)d_in[11];
    const float* pe = (const float*)d_in[12];
    float* out = (float*)d_out;

    unsigned short* ws = (unsigned short*)d_ws;
    const size_t NQ = (size_t)BB * HH * LL * DH;       // 4,194,304
    unsigned short* qbf = ws;
    unsigned short* kbf = qbf + NQ;
    unsigned short* vT  = kbf + NQ;
    unsigned short* attnb = vT + NQ;
    unsigned short* qpos = attnb + NQ;                 // bf16 [65536][301]
    unsigned long long* mbits =
        (unsigned long long*)(qpos + (size_t)BB * HH * LL * NPOS);

    const dim3 blk(256);
    const int M = BB * LL;                             // 4096

    pack_mask<<<dim3((BB * LL * LL / 64) * 64 / 256), blk, 0, stream>>>(mask, mbits);
    gemm_qkv<<<dim3(8, 32, 3), blk, 0, stream>>>(
        Q, K, V, Wq, Wk, Wv, bq, bk, bv, qbf, kbf, vT);
    gemm_mfma<3, true, false, true, 64><<<dim3(5, 512), blk, 0, stream>>>(
        qbf, pe, nullptr, qpos, BB * HH * LL, NPOS, DH, 1.0f);
    attn_mfma<<<dim3(BB * HH, LL / 32), dim3(256), 0, stream>>>(
        qbf, kbf, vT, qpos, mbits, attnb);
    gemm_mfma<0, false, false, true, 32><<<dim3(16, 32), blk, 0, stream>>>(
        attnb, Wo, bo, out, M, DD, DD, 1.0f);
}

// Round 21
// 266.107 us; speedup vs baseline: 1.0086x; 1.0086x over previous
//
#include <hip/hip_runtime.h>
#include <hip/hip_bf16.h>

// Problem constants (B=4, L=1024, D=1024, H=16, Dh=64, MAX_LEN=150)
#define BB 4
#define LL 1024
#define DD 1024
#define HH 16
#define DH 64
#define NPOS 301      // 2*MAX_LEN+1
#define MAXL 150
#define NEG_INF -1e30f

typedef __attribute__((ext_vector_type(4))) float f32x4;
typedef __attribute__((ext_vector_type(8))) short short8;

__device__ inline unsigned short f2b(float x) {
    __hip_bfloat16 h = __float2bfloat16(x);
    return *reinterpret_cast<unsigned short*>(&h);
}
__device__ inline unsigned pack2(float a, float b) {
    return (unsigned)f2b(a) | ((unsigned)f2b(b) << 16);
}
__device__ inline float b2f(unsigned short u) {
    return __uint_as_float((unsigned)u << 16);
}

// Load 8 contiguous elements as bf16x8, converting from f32 when F32=true.
template <bool F32>
__device__ inline short8 ld8(const void* p, size_t off) {
    if constexpr (F32) {
        const float* q = (const float*)p + off;
        float4 a = *reinterpret_cast<const float4*>(q);
        float4 b = *reinterpret_cast<const float4*>(q + 4);
        short8 r;
        r[0] = (short)f2b(a.x); r[1] = (short)f2b(a.y);
        r[2] = (short)f2b(a.z); r[3] = (short)f2b(a.w);
        r[4] = (short)f2b(b.x); r[5] = (short)f2b(b.y);
        r[6] = (short)f2b(b.z); r[7] = (short)f2b(b.w);
        return r;
    } else {
        return *reinterpret_cast<const short8*>((const unsigned short*)p + off);
    }
}

// ---------------------------------------------------------------------------
// Mask bit-pack: mask[b][q][k] (nonzero = masked) -> one bit per element.
// ---------------------------------------------------------------------------
__global__ __launch_bounds__(256) void pack_mask(const int* __restrict__ mask,
                                                 unsigned long long* __restrict__ bits)
{
    const int wid = (blockIdx.x * 256 + threadIdx.x) >> 6;   // global wave id
    const int lane = threadIdx.x & 63;
    const int v = mask[(size_t)wid * 64 + lane];
    const unsigned long long b = __ballot(v != 0);
    if (lane == 0) bits[wid] = b;
}

// ---------------------------------------------------------------------------
// bf16 MFMA GEMM core (128 x 64 tile) — r14-validated config for the final
// projection (BKT=32) and the qpos table (BKT=64, single K-step at K=64).
// EPI 0: f32 [M][N]; EPI 1: bf16 [bh][l][dh]; EPI 2: bf16 [bh][dh][l];
// EPI 3: bf16 plain [M][N] (GN guards N).
// ---------------------------------------------------------------------------
template <int BKT, bool GN, bool AF32, bool WF32>
__device__ __forceinline__ void gemm_body(
    const void* __restrict__ A, const void* __restrict__ W,
    const float* __restrict__ bias, void* __restrict__ Cout,
    int M, int N, int K, float oscale, int epi,
    int m0, int n0, unsigned short* As, unsigned short* Bs)
{
    constexpr int PAD = BKT + 8;
    const int tid = threadIdx.x;
    const int w = tid >> 6, lane = tid & 63;
    const int wr = w >> 1, wc = w & 1;
    const int g = lane >> 4, fr = lane & 15;

    f32x4 acc[4][2];
#pragma unroll
    for (int i = 0; i < 4; ++i)
#pragma unroll
        for (int j = 0; j < 2; ++j) acc[i][j] = (f32x4){0.f, 0.f, 0.f, 0.f};

    const int arow0 = tid >> 2, agg = (tid & 3) * 8;
    for (int k0 = 0; k0 < K; k0 += BKT) {
        if constexpr (BKT == 32) {
            short8 v0 = ld8<AF32>(A, (size_t)(m0 + arow0) * K + k0 + agg);
            short8 v1 = ld8<AF32>(A, (size_t)(m0 + arow0 + 64) * K + k0 + agg);
            int nr = n0 + arow0;
            if (GN && nr >= N) nr = N - 1;
            short8 bv = ld8<WF32>(W, (size_t)nr * K + k0 + agg);
            *reinterpret_cast<short8*>(&As[arow0 * PAD + agg]) = v0;
            *reinterpret_cast<short8*>(&As[(arow0 + 64) * PAD + agg]) = v1;
            *reinterpret_cast<short8*>(&Bs[arow0 * PAD + agg]) = bv;
        } else {
            short8 a00 = ld8<AF32>(A, (size_t)(m0 + arow0) * K + k0 + agg);
            short8 a01 = ld8<AF32>(A, (size_t)(m0 + arow0) * K + k0 + agg + 32);
            short8 a10 = ld8<AF32>(A, (size_t)(m0 + arow0 + 64) * K + k0 + agg);
            short8 a11 = ld8<AF32>(A, (size_t)(m0 + arow0 + 64) * K + k0 + agg + 32);
            int nr = n0 + arow0;
            if (GN && nr >= N) nr = N - 1;
            short8 b0 = ld8<WF32>(W, (size_t)nr * K + k0 + agg);
            short8 b1 = ld8<WF32>(W, (size_t)nr * K + k0 + agg + 32);
            *reinterpret_cast<short8*>(&As[arow0 * PAD + agg]) = a00;
            *reinterpret_cast<short8*>(&As[arow0 * PAD + agg + 32]) = a01;
            *reinterpret_cast<short8*>(&As[(arow0 + 64) * PAD + agg]) = a10;
            *reinterpret_cast<short8*>(&As[(arow0 + 64) * PAD + agg + 32]) = a11;
            *reinterpret_cast<short8*>(&Bs[arow0 * PAD + agg]) = b0;
            *reinterpret_cast<short8*>(&Bs[arow0 * PAD + agg + 32]) = b1;
        }
        __syncthreads();
#pragma unroll
        for (int kk = 0; kk < BKT / 32; ++kk) {
            short8 af[4], bf[2];
#pragma unroll
            for (int i = 0; i < 4; ++i)
                af[i] = *reinterpret_cast<const short8*>(
                    &As[(wr * 64 + i * 16 + fr) * PAD + kk * 32 + g * 8]);
#pragma unroll
            for (int j = 0; j < 2; ++j)
                bf[j] = *reinterpret_cast<const short8*>(
                    &Bs[(wc * 32 + j * 16 + fr) * PAD + kk * 32 + g * 8]);
#pragma unroll
            for (int i = 0; i < 4; ++i)
#pragma unroll
                for (int j = 0; j < 2; ++j)
                    acc[i][j] = __builtin_amdgcn_mfma_f32_16x16x32_bf16(
                        af[i], bf[j], acc[i][j], 0, 0, 0);
        }
        __syncthreads();
    }

#pragma unroll
    for (int i = 0; i < 4; ++i) {
#pragma unroll
        for (int j = 0; j < 2; ++j) {
#pragma unroll
            for (int r = 0; r < 4; ++r) {
                const int row = m0 + wr * 64 + i * 16 + g * 4 + r;
                const int col = n0 + wc * 32 + j * 16 + fr;
                if (GN && col >= N) continue;
                const float val = (acc[i][j][r] + (bias ? bias[col] : 0.f)) * oscale;
                if (epi == 0) {
                    ((float*)Cout)[(size_t)row * N + col] = val;
                } else if (epi == 1) {
                    const int b = row >> 10, l = row & 1023, hh = col >> 6, dh = col & 63;
                    ((unsigned short*)Cout)[(((size_t)(b * HH + hh)) * LL + l) * DH + dh] = f2b(val);
                } else if (epi == 2) {
                    const int b = row >> 10, l = row & 1023, hh = col >> 6, dh = col & 63;
                    ((unsigned short*)Cout)[(((size_t)(b * HH + hh)) * DH + dh) * LL + l] = f2b(val);
                } else {
                    ((unsigned short*)Cout)[(size_t)row * N + col] = f2b(val);
                }
            }
        }
    }
}

// Single-matrix GEMM (qpos table at BKT=64, final projection at BKT=32)
template <int EPI, bool GN, bool AF32, bool WF32, int BKT>
__global__ __launch_bounds__(256) void gemm_mfma(
    const void* __restrict__ A, const void* __restrict__ W,
    const float* __restrict__ bias, void* __restrict__ Cout,
    int M, int N, int K, float oscale)
{
    __shared__ alignas(16) unsigned short As[128 * (BKT + 8)];
    __shared__ alignas(16) unsigned short Bs[64 * (BKT + 8)];
    gemm_body<BKT, GN, AF32, WF32>(A, W, bias, Cout, M, N, K, oscale, EPI,
                                   blockIdx.y * 128, blockIdx.x * 64, As, Bs);
}

// ---------------------------------------------------------------------------
// 128 x 128 tile GEMM body (validated r19: 16 MFMA per 8 ds_read per K-step;
// viable because the z-merged launch gives 768 blocks = 3/CU co-resident).
// ---------------------------------------------------------------------------
template <bool AF32, bool WF32>
__device__ __forceinline__ void gemm_body128(
    const void* __restrict__ A, const void* __restrict__ W,
    const float* __restrict__ bias, void* __restrict__ Cout,
    int M, int N, int K, float oscale, int epi,
    int m0, int n0, unsigned short* As, unsigned short* Bs)
{
    const int tid = threadIdx.x;
    const int w = tid >> 6, lane = tid & 63;
    const int wr = w >> 1, wc = w & 1;
    const int g = lane >> 4, fr = lane & 15;

    f32x4 acc[4][4];
#pragma unroll
    for (int i = 0; i < 4; ++i)
#pragma unroll
        for (int j = 0; j < 4; ++j) acc[i][j] = (f32x4){0.f, 0.f, 0.f, 0.f};

    const int arow0 = tid >> 2, agg = (tid & 3) * 8;
    for (int k0 = 0; k0 < K; k0 += 32) {
        {
            short8 a0 = ld8<AF32>(A, (size_t)(m0 + arow0) * K + k0 + agg);
            short8 a1 = ld8<AF32>(A, (size_t)(m0 + arow0 + 64) * K + k0 + agg);
            short8 b0 = ld8<WF32>(W, (size_t)(n0 + arow0) * K + k0 + agg);
            short8 b1 = ld8<WF32>(W, (size_t)(n0 + arow0 + 64) * K + k0 + agg);
            *reinterpret_cast<short8*>(&As[arow0 * 40 + agg]) = a0;
            *reinterpret_cast<short8*>(&As[(arow0 + 64) * 40 + agg]) = a1;
            *reinterpret_cast<short8*>(&Bs[arow0 * 40 + agg]) = b0;
            *reinterpret_cast<short8*>(&Bs[(arow0 + 64) * 40 + agg]) = b1;
        }
        __syncthreads();
        short8 af[4], bf[4];
#pragma unroll
        for (int i = 0; i < 4; ++i)
            af[i] = *reinterpret_cast<const short8*>(
                &As[(wr * 64 + i * 16 + fr) * 40 + g * 8]);
#pragma unroll
        for (int j = 0; j < 4; ++j)
            bf[j] = *reinterpret_cast<const short8*>(
                &Bs[(wc * 64 + j * 16 + fr) * 40 + g * 8]);
#pragma unroll
        for (int i = 0; i < 4; ++i)
#pragma unroll
            for (int j = 0; j < 4; ++j)
                acc[i][j] = __builtin_amdgcn_mfma_f32_16x16x32_bf16(
                    af[i], bf[j], acc[i][j], 0, 0, 0);
        __syncthreads();
    }

#pragma unroll
    for (int i = 0; i < 4; ++i) {
#pragma unroll
        for (int j = 0; j < 4; ++j) {
#pragma unroll
            for (int r = 0; r < 4; ++r) {
                const int row = m0 + wr * 64 + i * 16 + g * 4 + r;
                const int col = n0 + wc * 64 + j * 16 + fr;
                const float val = (acc[i][j][r] + (bias ? bias[col] : 0.f)) * oscale;
                if (epi == 1) {
                    const int b = row >> 10, l = row & 1023, hh = col >> 6, dh = col & 63;
                    ((unsigned short*)Cout)[(((size_t)(b * HH + hh)) * LL + l) * DH + dh] = f2b(val);
                } else {
                    const int b = row >> 10, l = row & 1023, hh = col >> 6, dh = col & 63;
                    ((unsigned short*)Cout)[(((size_t)(b * HH + hh)) * DH + dh) * LL + l] = f2b(val);
                }
            }
        }
    }
}

// Merged Q/K/V projection, 128x128 tile (z selects matrix); 768 blocks.
__global__ __launch_bounds__(256) void gemm_qkv(
    const float* __restrict__ Q, const float* __restrict__ K,
    const float* __restrict__ V,
    const float* __restrict__ Wq, const float* __restrict__ Wk,
    const float* __restrict__ Wv,
    const float* __restrict__ bq, const float* __restrict__ bk,
    const float* __restrict__ bv,
    unsigned short* __restrict__ qbf, unsigned short* __restrict__ kbf,
    unsigned short* __restrict__ vT)
{
    __shared__ alignas(16) unsigned short As[128 * 40];
    __shared__ alignas(16) unsigned short Bs[128 * 40];
    const int z = blockIdx.z;
    const float* A = (z == 0) ? Q : (z == 1) ? K : V;
    const float* W = (z == 0) ? Wq : (z == 1) ? Wk : Wv;
    const float* bias = (z == 0) ? bq : (z == 1) ? bk : bv;
    void* Cout = (z == 0) ? (void*)qbf : (z == 1) ? (void*)kbf : (void*)vT;
    const int epi = (z == 2) ? 2 : 1;
    const float oscale = (z == 0) ? 0.125f : 1.0f;
    gemm_body128<true, true>(A, W, bias, Cout, BB * LL, DD, DD, oscale, epi,
                             blockIdx.y * 128, blockIdx.x * 128, As, Bs);
}

// ---------------------------------------------------------------------------
// MFMA attention — r14/r19 structure (135 us validated). r20's setprio was
// null (occupancy 31->44% with zero time change: latency-chain-bound, not
// occupancy-bound) and is REVERTED. Split-K (2 q-groups x 2 k-halves, 8
// tiles each), LDS qpos slab (19.3 KB, merge buffer aliased), bit-mask,
// banded gather, in-register online softmax, P via swizzled private LDS.
// ---------------------------------------------------------------------------
__global__ __launch_bounds__(256) void attn_mfma(
    const unsigned short* __restrict__ qbf,   // [bh][l][dh] bf16 (scaled 1/8)
    const unsigned short* __restrict__ kbf,   // [bh][l][dh] bf16
    const unsigned short* __restrict__ vT,    // [bh][dh][l] bf16
    const unsigned short* __restrict__ qpos,  // [bh*L][301] bf16 (scaled 1/8)
    const unsigned long long* __restrict__ mbits, // [b][q][L/64] bit-mask
    unsigned short* __restrict__ outb)        // [b][l][D] bf16
{
    const int bh = blockIdx.x;                // fast dim -> same-bh on one XCD
    const int qblk = blockIdx.y;
    const int b = bh >> 4, h = bh & 15;
    const int tid = threadIdx.x;
    const int w = tid >> 6;                   // 0..3
    const int qh = w & 1;                     // q-group
    const int kh = w >> 1;                    // k-half
    const int lane = tid & 63;
    const int g = lane >> 4;
    const int qc = lane & 15;
    const int gq = qblk * 32 + qh * 16 + qc;
    const int ql = qh * 16 + qc;              // local q row (0..31)

    __shared__ alignas(16) unsigned char Plds[4 * 2048];
    __shared__ alignas(16) unsigned short Qp[32 * NPOS];   // 19264 B; aliased
    float* Mrg = (float*)Qp;                  // as merge buf after 2nd barrier
    unsigned char* myP = Plds + w * 2048 + qc * 128;
    const int swz = (qc & 7) << 4;

    // ---- stage qpos slab (contiguous 32*301 bf16), coalesced ----
    {
        const unsigned short* qslab = qpos + ((size_t)bh * LL + (size_t)qblk * 32) * NPOS;
        for (int i = tid; i < (32 * NPOS) / 8; i += 256)
            *reinterpret_cast<short8*>(&Qp[i * 8]) =
                *reinterpret_cast<const short8*>(qslab + (size_t)i * 8);
    }

    const unsigned short* qrow = qbf + ((size_t)bh * LL + gq) * DH;
    const short8 qf0 = *reinterpret_cast<const short8*>(qrow + g * 8);
    const short8 qf1 = *reinterpret_cast<const short8*>(qrow + g * 8 + 32);

    const unsigned short* kb0 = kbf + (size_t)bh * LL * DH;
    const unsigned short* vb0 = vT + (size_t)bh * DH * LL;
    const unsigned long long* mwp = mbits + ((size_t)b * LL + gq) * (LL / 64);
    const unsigned short* qpr = &Qp[ql * NPOS];

    float mrun = -3.0e38f, lrun = 0.f;
    f32x4 o[4];
#pragma unroll
    for (int m = 0; m < 4; ++m) o[m] = (f32x4){0.f, 0.f, 0.f, 0.f};

    __syncthreads();                          // Qp ready (read-only in loop)
    const float c_left = b2f(qpr[300]);       // rel <= -150
    const float c_right = b2f(qpr[299]);      // rel >= +150

    // 8 tiles per wave, interleaved across k-halves
    for (int it = 0; it < 8; ++it) {
        const int kt = kh * 64 + it * 128;

        // ---- S^T = K . Q^T ----
        f32x4 s[4];
#pragma unroll
        for (int m = 0; m < 4; ++m) s[m] = (f32x4){0.f, 0.f, 0.f, 0.f};
#pragma unroll
        for (int m = 0; m < 4; ++m) {
            const unsigned short* krow = kb0 + (size_t)(kt + m * 16 + qc) * DH + g * 8;
            short8 a0 = *reinterpret_cast<const short8*>(krow);
            short8 a1 = *reinterpret_cast<const short8*>(krow + 32);
            s[m] = __builtin_amdgcn_mfma_f32_16x16x32_bf16(a0, qf0, s[m], 0, 0, 0);
            s[m] = __builtin_amdgcn_mfma_f32_16x16x32_bf16(a1, qf1, s[m], 0, 0, 0);
        }

        // ---- scores in place: banded qpos (LDS) + bit-mask ----
        const unsigned long long mw = mwp[kt >> 6];
        float tmax = -3.0e38f;
#pragma unroll
        for (int m = 0; m < 4; ++m) {
            const int kb = kt + m * 16 + g * 4;
            const unsigned msub = (unsigned)(mw >> (m * 16 + g * 4)) & 0xFu;
            const int p0 = kb - gq + 149;     // unclipped idx of r=0
            float rp0, rp1, rp2, rp3;
            if (p0 > 299) {                   // whole run right-saturated
                rp0 = rp1 = rp2 = rp3 = c_right;
            } else if (p0 < -3) {             // whole run left-saturated
                rp0 = rp1 = rp2 = rp3 = c_left;
            } else if (p0 >= 0 && p0 <= 296) { // strictly in band (LDS reads)
                rp0 = b2f(qpr[p0]);     rp1 = b2f(qpr[p0 + 1]);
                rp2 = b2f(qpr[p0 + 2]); rp3 = b2f(qpr[p0 + 3]);
            } else {                          // straddling band edge (rare)
                int i0 = p0 < 0 ? 300 : p0;
                int i1 = p0 + 1 < 0 ? 300 : (p0 + 1 > 299 ? 299 : p0 + 1);
                int i2 = p0 + 2 < 0 ? 300 : (p0 + 2 > 299 ? 299 : p0 + 2);
                int i3 = p0 + 3 > 299 ? 299 : p0 + 3;
                rp0 = b2f(qpr[i0]); rp1 = b2f(qpr[i1]);
                rp2 = b2f(qpr[i2]); rp3 = b2f(qpr[i3]);
            }
#pragma unroll
            for (int r = 0; r < 4; ++r) {
                const float rp = (r == 0 ? rp0 : r == 1 ? rp1 : r == 2 ? rp2 : rp3);
                float x = s[m][r] + rp;       // both pre-scaled by 1/8
                x = (msub >> r) & 1 ? NEG_INF : x;
                s[m][r] = x;
                tmax = fmaxf(tmax, x);
            }
        }

        // ---- online softmax (in-register, in-place exp) ----
        tmax = fmaxf(tmax, __shfl_xor(tmax, 16));
        tmax = fmaxf(tmax, __shfl_xor(tmax, 32));
        const float nm = fmaxf(mrun, tmax);
        const float al = __expf(mrun - nm);
        mrun = nm;
        float ls = 0.f;
#pragma unroll
        for (int m = 0; m < 4; ++m)
#pragma unroll
            for (int r = 0; r < 4; ++r) {
                const float p = __expf(s[m][r] - nm);
                s[m][r] = p;
                ls += p;
            }
        ls += __shfl_xor(ls, 16);
        ls += __shfl_xor(ls, 32);
        lrun = lrun * al + ls;
#pragma unroll
        for (int m = 0; m < 4; ++m) o[m] *= al;

        // ---- P -> bf16 -> private LDS (swizzled), re-read as B-frags ----
#pragma unroll
        for (int m = 0; m < 4; ++m) {
            *reinterpret_cast<unsigned*>(myP + ((32 * m + 8 * g) ^ swz)) = pack2(s[m][0], s[m][1]);
            *reinterpret_cast<unsigned*>(myP + ((32 * m + 8 * g + 4) ^ swz)) = pack2(s[m][2], s[m][3]);
        }
        const short8 pf0 = *reinterpret_cast<const short8*>(myP + ((16 * g) ^ swz));
        const short8 pf1 = *reinterpret_cast<const short8*>(myP + ((64 + 16 * g) ^ swz));

        // ---- O^T += V^T . P^T ----
#pragma unroll
        for (int m = 0; m < 4; ++m) {
            const unsigned short* vrow = vb0 + (size_t)(m * 16 + qc) * LL + kt + g * 8;
            short8 va0 = *reinterpret_cast<const short8*>(vrow);
            short8 va1 = *reinterpret_cast<const short8*>(vrow + 32);
            o[m] = __builtin_amdgcn_mfma_f32_16x16x32_bf16(va0, pf0, o[m], 0, 0, 0);
            o[m] = __builtin_amdgcn_mfma_f32_16x16x32_bf16(va1, pf1, o[m], 0, 0, 0);
        }
    }

    // ---- split-K merge (Mrg aliases Qp; barrier separates lifetimes) ----
    __syncthreads();                          // everyone done reading Qp
    if (kh == 1) {
        float* d = Mrg + ((size_t)qh * 64 + lane) * 18;
#pragma unroll
        for (int m = 0; m < 4; ++m)
#pragma unroll
            for (int r = 0; r < 4; ++r) d[m * 4 + r] = o[m][r];
        d[16] = mrun; d[17] = lrun;
    }
    __syncthreads();
    if (kh == 0) {
        const float* d = Mrg + ((size_t)qh * 64 + lane) * 18;
        const float m1 = d[16], l1 = d[17];
        const float M = fmaxf(mrun, m1);
        const float a0 = __expf(mrun - M), a1 = __expf(m1 - M);
        const float linv = 1.f / (lrun * a0 + l1 * a1);
        unsigned short* orow = outb + ((size_t)b * LL + gq) * DD + h * DH;
#pragma unroll
        for (int m = 0; m < 4; ++m) {
            ushort4 st;
            st.x = f2b((o[m][0] * a0 + d[m * 4 + 0] * a1) * linv);
            st.y = f2b((o[m][1] * a0 + d[m * 4 + 1] * a1) * linv);
            st.z = f2b((o[m][2] * a0 + d[m * 4 + 2] * a1) * linv);
            st.w = f2b((o[m][3] * a0 + d[m * 4 + 3] * a1) * linv);
            *reinterpret_cast<ushort4*>(orow + m * 16 + g * 4) = st;
        }
    }
}

// ---------------------------------------------------------------------------
// Inputs (dict order): 0 Q, 1 K, 2 V, 3 mask, 4 Wq, 5 bq, 6 Wk, 7 bk,
// 8 Wv, 9 bv, 10 Wo, 11 bo, 12 pos_emb.  Output: [B, L, D] float32.
// 5 dispatches. Workspace (bf16): qbf kbf vT attnb (4 x 4M) + qpos
// [65536][301] + mbits u64[65536] = ~72 MB.
// ---------------------------------------------------------------------------
extern "C" void kernel_launch(void* const* d_in, const int* in_sizes, int n_in,
                              void* d_out, int out_size, void* d_ws, size_t ws_size,
                              hipStream_t stream)
{
    const float* Q  = (const float*)d_in[0];
    const float* K  = (const float*)d_in[1];
    const float* V  = (const float*)d_in[2];
    const int* mask = (const int*)d_in[3];
    const float* Wq = (const float*)d_in[4];
    const float* bq = (const float*)d_in[5];
    const float* Wk = (const float*)d_in[6];
    const float* bk = (const float*)d_in[7];
    const float* Wv = (const float*)d_in[8];
    const float* bv = (const float*)d_in[9];
    const float* Wo = (const float*)d_in[10];
    const float* bo = (const float*)d_in[11];
    const float* pe = (const float*)d_in[12];
    float* out = (float*)d_out;

    unsigned short* ws = (unsigned short*)d_ws;
    const size_t NQ = (size_t)BB * HH * LL * DH;       // 4,194,304
    unsigned short* qbf = ws;
    unsigned short* kbf = qbf + NQ;
    unsigned short* vT  = kbf + NQ;
    unsigned short* attnb = vT + NQ;
    unsigned short* qpos = attnb + NQ;                 // bf16 [65536][301]
    unsigned long long* mbits =
        (unsigned long long*)(qpos + (size_t)BB * HH * LL * NPOS);

    const dim3 blk(256);
    const int M = BB * LL;                             // 4096

    pack_mask<<<dim3((BB * LL * LL / 64) * 64 / 256), blk, 0, stream>>>(mask, mbits);
    gemm_qkv<<<dim3(8, 32, 3), blk, 0, stream>>>(
        Q, K, V, Wq, Wk, Wv, bq, bk, bv, qbf, kbf, vT);
    gemm_mfma<3, true, false, true, 64><<<dim3(5, 512), blk, 0, stream>>>(
        qbf, pe, nullptr, qpos, BB * HH * LL, NPOS, DH, 1.0f);
    attn_mfma<<<dim3(BB * HH, LL / 32), dim3(256), 0, stream>>>(
        qbf, kbf, vT, qpos, mbits, attnb);
    gemm_mfma<0, false, false, true, 32><<<dim3(16, 32), blk, 0, stream>>>(
        attnb, Wo, bo, out, M, DD, DD, 1.0f);
}

// Round 22
// 247.368 us; speedup vs baseline: 1.0850x; 1.0758x over previous
//
#include <hip/hip_runtime.h>
#include <hip/hip_bf16.h>

// Problem constants (B=4, L=1024, D=1024, H=16, Dh=64, MAX_LEN=150)
#define BB 4
#define LL 1024
#define DD 1024
#define HH 16
#define DH 64
#define NPOS 301      // 2*MAX_LEN+1
#define MAXL 150
#define NEG_INF -1e30f

typedef __attribute__((ext_vector_type(4))) float f32x4;
typedef __attribute__((ext_vector_type(8))) short short8;

__device__ inline unsigned short f2b(float x) {
    __hip_bfloat16 h = __float2bfloat16(x);
    return *reinterpret_cast<unsigned short*>(&h);
}
__device__ inline unsigned pack2(float a, float b) {
    return (unsigned)f2b(a) | ((unsigned)f2b(b) << 16);
}
__device__ inline float b2f(unsigned short u) {
    return __uint_as_float((unsigned)u << 16);
}

// Load 8 contiguous elements as bf16x8, converting from f32 when F32=true.
template <bool F32>
__device__ inline short8 ld8(const void* p, size_t off) {
    if constexpr (F32) {
        const float* q = (const float*)p + off;
        float4 a = *reinterpret_cast<const float4*>(q);
        float4 b = *reinterpret_cast<const float4*>(q + 4);
        short8 r;
        r[0] = (short)f2b(a.x); r[1] = (short)f2b(a.y);
        r[2] = (short)f2b(a.z); r[3] = (short)f2b(a.w);
        r[4] = (short)f2b(b.x); r[5] = (short)f2b(b.y);
        r[6] = (short)f2b(b.z); r[7] = (short)f2b(b.w);
        return r;
    } else {
        return *reinterpret_cast<const short8*>((const unsigned short*)p + off);
    }
}

// ---------------------------------------------------------------------------
// Mask bit-pack: mask[b][q][k] (nonzero = masked) -> one bit per element.
// ---------------------------------------------------------------------------
__global__ __launch_bounds__(256) void pack_mask(const int* __restrict__ mask,
                                                 unsigned long long* __restrict__ bits)
{
    const int wid = (blockIdx.x * 256 + threadIdx.x) >> 6;   // global wave id
    const int lane = threadIdx.x & 63;
    const int v = mask[(size_t)wid * 64 + lane];
    const unsigned long long b = __ballot(v != 0);
    if (lane == 0) bits[wid] = b;
}

// ---------------------------------------------------------------------------
// bf16 MFMA GEMM core (128 x 64 tile) — r14-validated config for the final
// projection (BKT=32) and the qpos table (BKT=64, single K-step at K=64).
// EPI 0: f32 [M][N]; EPI 1: bf16 [bh][l][dh]; EPI 2: bf16 [bh][dh][l];
// EPI 3: bf16 plain [M][N] (GN guards N).
// ---------------------------------------------------------------------------
template <int BKT, bool GN, bool AF32, bool WF32>
__device__ __forceinline__ void gemm_body(
    const void* __restrict__ A, const void* __restrict__ W,
    const float* __restrict__ bias, void* __restrict__ Cout,
    int M, int N, int K, float oscale, int epi,
    int m0, int n0, unsigned short* As, unsigned short* Bs)
{
    constexpr int PAD = BKT + 8;
    const int tid = threadIdx.x;
    const int w = tid >> 6, lane = tid & 63;
    const int wr = w >> 1, wc = w & 1;
    const int g = lane >> 4, fr = lane & 15;

    f32x4 acc[4][2];
#pragma unroll
    for (int i = 0; i < 4; ++i)
#pragma unroll
        for (int j = 0; j < 2; ++j) acc[i][j] = (f32x4){0.f, 0.f, 0.f, 0.f};

    const int arow0 = tid >> 2, agg = (tid & 3) * 8;
    for (int k0 = 0; k0 < K; k0 += BKT) {
        if constexpr (BKT == 32) {
            short8 v0 = ld8<AF32>(A, (size_t)(m0 + arow0) * K + k0 + agg);
            short8 v1 = ld8<AF32>(A, (size_t)(m0 + arow0 + 64) * K + k0 + agg);
            int nr = n0 + arow0;
            if (GN && nr >= N) nr = N - 1;
            short8 bv = ld8<WF32>(W, (size_t)nr * K + k0 + agg);
            *reinterpret_cast<short8*>(&As[arow0 * PAD + agg]) = v0;
            *reinterpret_cast<short8*>(&As[(arow0 + 64) * PAD + agg]) = v1;
            *reinterpret_cast<short8*>(&Bs[arow0 * PAD + agg]) = bv;
        } else {
            short8 a00 = ld8<AF32>(A, (size_t)(m0 + arow0) * K + k0 + agg);
            short8 a01 = ld8<AF32>(A, (size_t)(m0 + arow0) * K + k0 + agg + 32);
            short8 a10 = ld8<AF32>(A, (size_t)(m0 + arow0 + 64) * K + k0 + agg);
            short8 a11 = ld8<AF32>(A, (size_t)(m0 + arow0 + 64) * K + k0 + agg + 32);
            int nr = n0 + arow0;
            if (GN && nr >= N) nr = N - 1;
            short8 b0 = ld8<WF32>(W, (size_t)nr * K + k0 + agg);
            short8 b1 = ld8<WF32>(W, (size_t)nr * K + k0 + agg + 32);
            *reinterpret_cast<short8*>(&As[arow0 * PAD + agg]) = a00;
            *reinterpret_cast<short8*>(&As[arow0 * PAD + agg + 32]) = a01;
            *reinterpret_cast<short8*>(&As[(arow0 + 64) * PAD + agg]) = a10;
            *reinterpret_cast<short8*>(&As[(arow0 + 64) * PAD + agg + 32]) = a11;
            *reinterpret_cast<short8*>(&Bs[arow0 * PAD + agg]) = b0;
            *reinterpret_cast<short8*>(&Bs[arow0 * PAD + agg + 32]) = b1;
        }
        __syncthreads();
#pragma unroll
        for (int kk = 0; kk < BKT / 32; ++kk) {
            short8 af[4], bf[2];
#pragma unroll
            for (int i = 0; i < 4; ++i)
                af[i] = *reinterpret_cast<const short8*>(
                    &As[(wr * 64 + i * 16 + fr) * PAD + kk * 32 + g * 8]);
#pragma unroll
            for (int j = 0; j < 2; ++j)
                bf[j] = *reinterpret_cast<const short8*>(
                    &Bs[(wc * 32 + j * 16 + fr) * PAD + kk * 32 + g * 8]);
#pragma unroll
            for (int i = 0; i < 4; ++i)
#pragma unroll
                for (int j = 0; j < 2; ++j)
                    acc[i][j] = __builtin_amdgcn_mfma_f32_16x16x32_bf16(
                        af[i], bf[j], acc[i][j], 0, 0, 0);
        }
        __syncthreads();
    }

#pragma unroll
    for (int i = 0; i < 4; ++i) {
#pragma unroll
        for (int j = 0; j < 2; ++j) {
#pragma unroll
            for (int r = 0; r < 4; ++r) {
                const int row = m0 + wr * 64 + i * 16 + g * 4 + r;
                const int col = n0 + wc * 32 + j * 16 + fr;
                if (GN && col >= N) continue;
                const float val = (acc[i][j][r] + (bias ? bias[col] : 0.f)) * oscale;
                if (epi == 0) {
                    ((float*)Cout)[(size_t)row * N + col] = val;
                } else if (epi == 1) {
                    const int b = row >> 10, l = row & 1023, hh = col >> 6, dh = col & 63;
                    ((unsigned short*)Cout)[(((size_t)(b * HH + hh)) * LL + l) * DH + dh] = f2b(val);
                } else if (epi == 2) {
                    const int b = row >> 10, l = row & 1023, hh = col >> 6, dh = col & 63;
                    ((unsigned short*)Cout)[(((size_t)(b * HH + hh)) * DH + dh) * LL + l] = f2b(val);
                } else {
                    ((unsigned short*)Cout)[(size_t)row * N + col] = f2b(val);
                }
            }
        }
    }
}

// Single-matrix GEMM (qpos table at BKT=64, final projection at BKT=32)
template <int EPI, bool GN, bool AF32, bool WF32, int BKT>
__global__ __launch_bounds__(256) void gemm_mfma(
    const void* __restrict__ A, const void* __restrict__ W,
    const float* __restrict__ bias, void* __restrict__ Cout,
    int M, int N, int K, float oscale)
{
    __shared__ alignas(16) unsigned short As[128 * (BKT + 8)];
    __shared__ alignas(16) unsigned short Bs[64 * (BKT + 8)];
    gemm_body<BKT, GN, AF32, WF32>(A, W, bias, Cout, M, N, K, oscale, EPI,
                                   blockIdx.y * 128, blockIdx.x * 64, As, Bs);
}

// ---------------------------------------------------------------------------
// 128 x 128 tile GEMM body (validated r19: 16 MFMA per 8 ds_read per K-step;
// viable because the z-merged launch gives 768 blocks = 3/CU co-resident).
// ---------------------------------------------------------------------------
template <bool AF32, bool WF32>
__device__ __forceinline__ void gemm_body128(
    const void* __restrict__ A, const void* __restrict__ W,
    const float* __restrict__ bias, void* __restrict__ Cout,
    int M, int N, int K, float oscale, int epi,
    int m0, int n0, unsigned short* As, unsigned short* Bs)
{
    const int tid = threadIdx.x;
    const int w = tid >> 6, lane = tid & 63;
    const int wr = w >> 1, wc = w & 1;
    const int g = lane >> 4, fr = lane & 15;

    f32x4 acc[4][4];
#pragma unroll
    for (int i = 0; i < 4; ++i)
#pragma unroll
        for (int j = 0; j < 4; ++j) acc[i][j] = (f32x4){0.f, 0.f, 0.f, 0.f};

    const int arow0 = tid >> 2, agg = (tid & 3) * 8;
    for (int k0 = 0; k0 < K; k0 += 32) {
        {
            short8 a0 = ld8<AF32>(A, (size_t)(m0 + arow0) * K + k0 + agg);
            short8 a1 = ld8<AF32>(A, (size_t)(m0 + arow0 + 64) * K + k0 + agg);
            short8 b0 = ld8<WF32>(W, (size_t)(n0 + arow0) * K + k0 + agg);
            short8 b1 = ld8<WF32>(W, (size_t)(n0 + arow0 + 64) * K + k0 + agg);
            *reinterpret_cast<short8*>(&As[arow0 * 40 + agg]) = a0;
            *reinterpret_cast<short8*>(&As[(arow0 + 64) * 40 + agg]) = a1;
            *reinterpret_cast<short8*>(&Bs[arow0 * 40 + agg]) = b0;
            *reinterpret_cast<short8*>(&Bs[(arow0 + 64) * 40 + agg]) = b1;
        }
        __syncthreads();
        short8 af[4], bf[4];
#pragma unroll
        for (int i = 0; i < 4; ++i)
            af[i] = *reinterpret_cast<const short8*>(
                &As[(wr * 64 + i * 16 + fr) * 40 + g * 8]);
#pragma unroll
        for (int j = 0; j < 4; ++j)
            bf[j] = *reinterpret_cast<const short8*>(
                &Bs[(wc * 64 + j * 16 + fr) * 40 + g * 8]);
#pragma unroll
        for (int i = 0; i < 4; ++i)
#pragma unroll
            for (int j = 0; j < 4; ++j)
                acc[i][j] = __builtin_amdgcn_mfma_f32_16x16x32_bf16(
                    af[i], bf[j], acc[i][j], 0, 0, 0);
        __syncthreads();
    }

#pragma unroll
    for (int i = 0; i < 4; ++i) {
#pragma unroll
        for (int j = 0; j < 4; ++j) {
#pragma unroll
            for (int r = 0; r < 4; ++r) {
                const int row = m0 + wr * 64 + i * 16 + g * 4 + r;
                const int col = n0 + wc * 64 + j * 16 + fr;
                const float val = (acc[i][j][r] + (bias ? bias[col] : 0.f)) * oscale;
                if (epi == 1) {
                    const int b = row >> 10, l = row & 1023, hh = col >> 6, dh = col & 63;
                    ((unsigned short*)Cout)[(((size_t)(b * HH + hh)) * LL + l) * DH + dh] = f2b(val);
                } else {
                    const int b = row >> 10, l = row & 1023, hh = col >> 6, dh = col & 63;
                    ((unsigned short*)Cout)[(((size_t)(b * HH + hh)) * DH + dh) * LL + l] = f2b(val);
                }
            }
        }
    }
}

// Merged Q/K/V projection, 128x128 tile (z selects matrix); 768 blocks.
// ROUND 22: grid axes SWAPPED (x = M-tile, y = N-tile). The 8 blocks sharing
// one 512 KB f32 A-panel now have linear ids congruent mod 8 -> land on the
// SAME XCD L2 (T1): A fetched once per XCD instead of 8x (r17 FETCH showed
// ~3.4x A over-fetch with the old order). Pure index permutation, same math.
__global__ __launch_bounds__(256) void gemm_qkv(
    const float* __restrict__ Q, const float* __restrict__ K,
    const float* __restrict__ V,
    const float* __restrict__ Wq, const float* __restrict__ Wk,
    const float* __restrict__ Wv,
    const float* __restrict__ bq, const float* __restrict__ bk,
    const float* __restrict__ bv,
    unsigned short* __restrict__ qbf, unsigned short* __restrict__ kbf,
    unsigned short* __restrict__ vT)
{
    __shared__ alignas(16) unsigned short As[128 * 40];
    __shared__ alignas(16) unsigned short Bs[128 * 40];
    const int z = blockIdx.z;
    const float* A = (z == 0) ? Q : (z == 1) ? K : V;
    const float* W = (z == 0) ? Wq : (z == 1) ? Wk : Wv;
    const float* bias = (z == 0) ? bq : (z == 1) ? bk : bv;
    void* Cout = (z == 0) ? (void*)qbf : (z == 1) ? (void*)kbf : (void*)vT;
    const int epi = (z == 2) ? 2 : 1;
    const float oscale = (z == 0) ? 0.125f : 1.0f;
    gemm_body128<true, true>(A, W, bias, Cout, BB * LL, DD, DD, oscale, epi,
                             blockIdx.x * 128, blockIdx.y * 128, As, Bs);
}

// ---------------------------------------------------------------------------
// MFMA attention — r14/r19 structure (135 us validated; setprio null r20,
// reverted). Split-K (2 q-groups x 2 k-halves, 8 tiles each), LDS qpos slab
// (19.3 KB, merge buffer aliased), bit-mask, banded gather, in-register
// online softmax, P via swizzled private LDS.
// ---------------------------------------------------------------------------
__global__ __launch_bounds__(256) void attn_mfma(
    const unsigned short* __restrict__ qbf,   // [bh][l][dh] bf16 (scaled 1/8)
    const unsigned short* __restrict__ kbf,   // [bh][l][dh] bf16
    const unsigned short* __restrict__ vT,    // [bh][dh][l] bf16
    const unsigned short* __restrict__ qpos,  // [bh*L][301] bf16 (scaled 1/8)
    const unsigned long long* __restrict__ mbits, // [b][q][L/64] bit-mask
    unsigned short* __restrict__ outb)        // [b][l][D] bf16
{
    const int bh = blockIdx.x;                // fast dim -> same-bh on one XCD
    const int qblk = blockIdx.y;
    const int b = bh >> 4, h = bh & 15;
    const int tid = threadIdx.x;
    const int w = tid >> 6;                   // 0..3
    const int qh = w & 1;                     // q-group
    const int kh = w >> 1;                    // k-half
    const int lane = tid & 63;
    const int g = lane >> 4;
    const int qc = lane & 15;
    const int gq = qblk * 32 + qh * 16 + qc;
    const int ql = qh * 16 + qc;              // local q row (0..31)

    __shared__ alignas(16) unsigned char Plds[4 * 2048];
    __shared__ alignas(16) unsigned short Qp[32 * NPOS];   // 19264 B; aliased
    float* Mrg = (float*)Qp;                  // as merge buf after 2nd barrier
    unsigned char* myP = Plds + w * 2048 + qc * 128;
    const int swz = (qc & 7) << 4;

    // ---- stage qpos slab (contiguous 32*301 bf16), coalesced ----
    {
        const unsigned short* qslab = qpos + ((size_t)bh * LL + (size_t)qblk * 32) * NPOS;
        for (int i = tid; i < (32 * NPOS) / 8; i += 256)
            *reinterpret_cast<short8*>(&Qp[i * 8]) =
                *reinterpret_cast<const short8*>(qslab + (size_t)i * 8);
    }

    const unsigned short* qrow = qbf + ((size_t)bh * LL + gq) * DH;
    const short8 qf0 = *reinterpret_cast<const short8*>(qrow + g * 8);
    const short8 qf1 = *reinterpret_cast<const short8*>(qrow + g * 8 + 32);

    const unsigned short* kb0 = kbf + (size_t)bh * LL * DH;
    const unsigned short* vb0 = vT + (size_t)bh * DH * LL;
    const unsigned long long* mwp = mbits + ((size_t)b * LL + gq) * (LL / 64);
    const unsigned short* qpr = &Qp[ql * NPOS];

    float mrun = -3.0e38f, lrun = 0.f;
    f32x4 o[4];
#pragma unroll
    for (int m = 0; m < 4; ++m) o[m] = (f32x4){0.f, 0.f, 0.f, 0.f};

    __syncthreads();                          // Qp ready (read-only in loop)
    const float c_left = b2f(qpr[300]);       // rel <= -150
    const float c_right = b2f(qpr[299]);      // rel >= +150

    // 8 tiles per wave, interleaved across k-halves
    for (int it = 0; it < 8; ++it) {
        const int kt = kh * 64 + it * 128;

        // ---- S^T = K . Q^T ----
        f32x4 s[4];
#pragma unroll
        for (int m = 0; m < 4; ++m) s[m] = (f32x4){0.f, 0.f, 0.f, 0.f};
#pragma unroll
        for (int m = 0; m < 4; ++m) {
            const unsigned short* krow = kb0 + (size_t)(kt + m * 16 + qc) * DH + g * 8;
            short8 a0 = *reinterpret_cast<const short8*>(krow);
            short8 a1 = *reinterpret_cast<const short8*>(krow + 32);
            s[m] = __builtin_amdgcn_mfma_f32_16x16x32_bf16(a0, qf0, s[m], 0, 0, 0);
            s[m] = __builtin_amdgcn_mfma_f32_16x16x32_bf16(a1, qf1, s[m], 0, 0, 0);
        }

        // ---- scores in place: banded qpos (LDS) + bit-mask ----
        const unsigned long long mw = mwp[kt >> 6];
        float tmax = -3.0e38f;
#pragma unroll
        for (int m = 0; m < 4; ++m) {
            const int kb = kt + m * 16 + g * 4;
            const unsigned msub = (unsigned)(mw >> (m * 16 + g * 4)) & 0xFu;
            const int p0 = kb - gq + 149;     // unclipped idx of r=0
            float rp0, rp1, rp2, rp3;
            if (p0 > 299) {                   // whole run right-saturated
                rp0 = rp1 = rp2 = rp3 = c_right;
            } else if (p0 < -3) {             // whole run left-saturated
                rp0 = rp1 = rp2 = rp3 = c_left;
            } else if (p0 >= 0 && p0 <= 296) { // strictly in band (LDS reads)
                rp0 = b2f(qpr[p0]);     rp1 = b2f(qpr[p0 + 1]);
                rp2 = b2f(qpr[p0 + 2]); rp3 = b2f(qpr[p0 + 3]);
            } else {                          // straddling band edge (rare)
                int i0 = p0 < 0 ? 300 : p0;
                int i1 = p0 + 1 < 0 ? 300 : (p0 + 1 > 299 ? 299 : p0 + 1);
                int i2 = p0 + 2 < 0 ? 300 : (p0 + 2 > 299 ? 299 : p0 + 2);
                int i3 = p0 + 3 > 299 ? 299 : p0 + 3;
                rp0 = b2f(qpr[i0]); rp1 = b2f(qpr[i1]);
                rp2 = b2f(qpr[i2]); rp3 = b2f(qpr[i3]);
            }
#pragma unroll
            for (int r = 0; r < 4; ++r) {
                const float rp = (r == 0 ? rp0 : r == 1 ? rp1 : r == 2 ? rp2 : rp3);
                float x = s[m][r] + rp;       // both pre-scaled by 1/8
                x = (msub >> r) & 1 ? NEG_INF : x;
                s[m][r] = x;
                tmax = fmaxf(tmax, x);
            }
        }

        // ---- online softmax (in-register, in-place exp) ----
        tmax = fmaxf(tmax, __shfl_xor(tmax, 16));
        tmax = fmaxf(tmax, __shfl_xor(tmax, 32));
        const float nm = fmaxf(mrun, tmax);
        const float al = __expf(mrun - nm);
        mrun = nm;
        float ls = 0.f;
#pragma unroll
        for (int m = 0; m < 4; ++m)
#pragma unroll
            for (int r = 0; r < 4; ++r) {
                const float p = __expf(s[m][r] - nm);
                s[m][r] = p;
                ls += p;
            }
        ls += __shfl_xor(ls, 16);
        ls += __shfl_xor(ls, 32);
        lrun = lrun * al + ls;
#pragma unroll
        for (int m = 0; m < 4; ++m) o[m] *= al;

        // ---- P -> bf16 -> private LDS (swizzled), re-read as B-frags ----
#pragma unroll
        for (int m = 0; m < 4; ++m) {
            *reinterpret_cast<unsigned*>(myP + ((32 * m + 8 * g) ^ swz)) = pack2(s[m][0], s[m][1]);
            *reinterpret_cast<unsigned*>(myP + ((32 * m + 8 * g + 4) ^ swz)) = pack2(s[m][2], s[m][3]);
        }
        const short8 pf0 = *reinterpret_cast<const short8*>(myP + ((16 * g) ^ swz));
        const short8 pf1 = *reinterpret_cast<const short8*>(myP + ((64 + 16 * g) ^ swz));

        // ---- O^T += V^T . P^T ----
#pragma unroll
        for (int m = 0; m < 4; ++m) {
            const unsigned short* vrow = vb0 + (size_t)(m * 16 + qc) * LL + kt + g * 8;
            short8 va0 = *reinterpret_cast<const short8*>(vrow);
            short8 va1 = *reinterpret_cast<const short8*>(vrow + 32);
            o[m] = __builtin_amdgcn_mfma_f32_16x16x32_bf16(va0, pf0, o[m], 0, 0, 0);
            o[m] = __builtin_amdgcn_mfma_f32_16x16x32_bf16(va1, pf1, o[m], 0, 0, 0);
        }
    }

    // ---- split-K merge (Mrg aliases Qp; barrier separates lifetimes) ----
    __syncthreads();                          // everyone done reading Qp
    if (kh == 1) {
        float* d = Mrg + ((size_t)qh * 64 + lane) * 18;
#pragma unroll
        for (int m = 0; m < 4; ++m)
#pragma unroll
            for (int r = 0; r < 4; ++r) d[m * 4 + r] = o[m][r];
        d[16] = mrun; d[17] = lrun;
    }
    __syncthreads();
    if (kh == 0) {
        const float* d = Mrg + ((size_t)qh * 64 + lane) * 18;
        const float m1 = d[16], l1 = d[17];
        const float M = fmaxf(mrun, m1);
        const float a0 = __expf(mrun - M), a1 = __expf(m1 - M);
        const float linv = 1.f / (lrun * a0 + l1 * a1);
        unsigned short* orow = outb + ((size_t)b * LL + gq) * DD + h * DH;
#pragma unroll
        for (int m = 0; m < 4; ++m) {
            ushort4 st;
            st.x = f2b((o[m][0] * a0 + d[m * 4 + 0] * a1) * linv);
            st.y = f2b((o[m][1] * a0 + d[m * 4 + 1] * a1) * linv);
            st.z = f2b((o[m][2] * a0 + d[m * 4 + 2] * a1) * linv);
            st.w = f2b((o[m][3] * a0 + d[m * 4 + 3] * a1) * linv);
            *reinterpret_cast<ushort4*>(orow + m * 16 + g * 4) = st;
        }
    }
}

// ---------------------------------------------------------------------------
// Inputs (dict order): 0 Q, 1 K, 2 V, 3 mask, 4 Wq, 5 bq, 6 Wk, 7 bk,
// 8 Wv, 9 bv, 10 Wo, 11 bo, 12 pos_emb.  Output: [B, L, D] float32.
// 5 dispatches. Workspace (bf16): qbf kbf vT attnb (4 x 4M) + qpos
// [65536][301] + mbits u64[65536] = ~72 MB.
// ---------------------------------------------------------------------------
extern "C" void kernel_launch(void* const* d_in, const int* in_sizes, int n_in,
                              void* d_out, int out_size, void* d_ws, size_t ws_size,
                              hipStream_t stream)
{
    const float* Q  = (const float*)d_in[0];
    const float* K  = (const float*)d_in[1];
    const float* V  = (const float*)d_in[2];
    const int* mask = (const int*)d_in[3];
    const float* Wq = (const float*)d_in[4];
    const float* bq = (const float*)d_in[5];
    const float* Wk = (const float*)d_in[6];
    const float* bk = (const float*)d_in[7];
    const float* Wv = (const float*)d_in[8];
    const float* bv = (const float*)d_in[9];
    const float* Wo = (const float*)d_in[10];
    const float* bo = (const float*)d_in[11];
    const float* pe = (const float*)d_in[12];
    float* out = (float*)d_out;

    unsigned short* ws = (unsigned short*)d_ws;
    const size_t NQ = (size_t)BB * HH * LL * DH;       // 4,194,304
    unsigned short* qbf = ws;
    unsigned short* kbf = qbf + NQ;
    unsigned short* vT  = kbf + NQ;
    unsigned short* attnb = vT + NQ;
    unsigned short* qpos = attnb + NQ;                 // bf16 [65536][301]
    unsigned long long* mbits =
        (unsigned long long*)(qpos + (size_t)BB * HH * LL * NPOS);

    const dim3 blk(256);
    const int M = BB * LL;                             // 4096

    pack_mask<<<dim3((BB * LL * LL / 64) * 64 / 256), blk, 0, stream>>>(mask, mbits);
    gemm_qkv<<<dim3(32, 8, 3), blk, 0, stream>>>(
        Q, K, V, Wq, Wk, Wv, bq, bk, bv, qbf, kbf, vT);
    gemm_mfma<3, true, false, true, 64><<<dim3(5, 512), blk, 0, stream>>>(
        qbf, pe, nullptr, qpos, BB * HH * LL, NPOS, DH, 1.0f);
    attn_mfma<<<dim3(BB * HH, LL / 32), dim3(256), 0, stream>>>(
        qbf, kbf, vT, qpos, mbits, attnb);
    gemm_mfma<0, false, false, true, 32><<<dim3(16, 32), blk, 0, stream>>>(
        attnb, Wo, bo, out, M, DD, DD, 1.0f);
}

// Round 23
// 244.054 us; speedup vs baseline: 1.0997x; 1.0136x over previous
//
#include <hip/hip_runtime.h>
#include <hip/hip_bf16.h>

// Problem constants (B=4, L=1024, D=1024, H=16, Dh=64, MAX_LEN=150)
#define BB 4
#define LL 1024
#define DD 1024
#define HH 16
#define DH 64
#define NPOS 301      // 2*MAX_LEN+1
#define MAXL 150
#define NEG_INF -1e30f

typedef __attribute__((ext_vector_type(4))) float f32x4;
typedef __attribute__((ext_vector_type(8))) short short8;

__device__ inline unsigned short f2b(float x) {
    __hip_bfloat16 h = __float2bfloat16(x);
    return *reinterpret_cast<unsigned short*>(&h);
}
__device__ inline unsigned pack2(float a, float b) {
    return (unsigned)f2b(a) | ((unsigned)f2b(b) << 16);
}
__device__ inline float b2f(unsigned short u) {
    return __uint_as_float((unsigned)u << 16);
}

// Load 8 contiguous elements as bf16x8, converting from f32 when F32=true.
template <bool F32>
__device__ inline short8 ld8(const void* p, size_t off) {
    if constexpr (F32) {
        const float* q = (const float*)p + off;
        float4 a = *reinterpret_cast<const float4*>(q);
        float4 b = *reinterpret_cast<const float4*>(q + 4);
        short8 r;
        r[0] = (short)f2b(a.x); r[1] = (short)f2b(a.y);
        r[2] = (short)f2b(a.z); r[3] = (short)f2b(a.w);
        r[4] = (short)f2b(b.x); r[5] = (short)f2b(b.y);
        r[6] = (short)f2b(b.z); r[7] = (short)f2b(b.w);
        return r;
    } else {
        return *reinterpret_cast<const short8*>((const unsigned short*)p + off);
    }
}

// ---------------------------------------------------------------------------
// Mask bit-pack: mask[b][q][k] (nonzero = masked) -> one bit per element.
// ---------------------------------------------------------------------------
__global__ __launch_bounds__(256) void pack_mask(const int* __restrict__ mask,
                                                 unsigned long long* __restrict__ bits)
{
    const int wid = (blockIdx.x * 256 + threadIdx.x) >> 6;   // global wave id
    const int lane = threadIdx.x & 63;
    const int v = mask[(size_t)wid * 64 + lane];
    const unsigned long long b = __ballot(v != 0);
    if (lane == 0) bits[wid] = b;
}

// ---------------------------------------------------------------------------
// bf16 MFMA GEMM core (128 x 64 tile) — r14-validated config for the final
// projection (BKT=32) and the qpos table (BKT=64, single K-step at K=64).
// EPI 0: f32 [M][N]; EPI 1: bf16 [bh][l][dh]; EPI 2: bf16 [bh][dh][l];
// EPI 3: bf16 plain [M][N] (GN guards N).
// ---------------------------------------------------------------------------
template <int BKT, bool GN, bool AF32, bool WF32>
__device__ __forceinline__ void gemm_body(
    const void* __restrict__ A, const void* __restrict__ W,
    const float* __restrict__ bias, void* __restrict__ Cout,
    int M, int N, int K, float oscale, int epi,
    int m0, int n0, unsigned short* As, unsigned short* Bs)
{
    constexpr int PAD = BKT + 8;
    const int tid = threadIdx.x;
    const int w = tid >> 6, lane = tid & 63;
    const int wr = w >> 1, wc = w & 1;
    const int g = lane >> 4, fr = lane & 15;

    f32x4 acc[4][2];
#pragma unroll
    for (int i = 0; i < 4; ++i)
#pragma unroll
        for (int j = 0; j < 2; ++j) acc[i][j] = (f32x4){0.f, 0.f, 0.f, 0.f};

    const int arow0 = tid >> 2, agg = (tid & 3) * 8;
    for (int k0 = 0; k0 < K; k0 += BKT) {
        if constexpr (BKT == 32) {
            short8 v0 = ld8<AF32>(A, (size_t)(m0 + arow0) * K + k0 + agg);
            short8 v1 = ld8<AF32>(A, (size_t)(m0 + arow0 + 64) * K + k0 + agg);
            int nr = n0 + arow0;
            if (GN && nr >= N) nr = N - 1;
            short8 bv = ld8<WF32>(W, (size_t)nr * K + k0 + agg);
            *reinterpret_cast<short8*>(&As[arow0 * PAD + agg]) = v0;
            *reinterpret_cast<short8*>(&As[(arow0 + 64) * PAD + agg]) = v1;
            *reinterpret_cast<short8*>(&Bs[arow0 * PAD + agg]) = bv;
        } else {
            short8 a00 = ld8<AF32>(A, (size_t)(m0 + arow0) * K + k0 + agg);
            short8 a01 = ld8<AF32>(A, (size_t)(m0 + arow0) * K + k0 + agg + 32);
            short8 a10 = ld8<AF32>(A, (size_t)(m0 + arow0 + 64) * K + k0 + agg);
            short8 a11 = ld8<AF32>(A, (size_t)(m0 + arow0 + 64) * K + k0 + agg + 32);
            int nr = n0 + arow0;
            if (GN && nr >= N) nr = N - 1;
            short8 b0 = ld8<WF32>(W, (size_t)nr * K + k0 + agg);
            short8 b1 = ld8<WF32>(W, (size_t)nr * K + k0 + agg + 32);
            *reinterpret_cast<short8*>(&As[arow0 * PAD + agg]) = a00;
            *reinterpret_cast<short8*>(&As[arow0 * PAD + agg + 32]) = a01;
            *reinterpret_cast<short8*>(&As[(arow0 + 64) * PAD + agg]) = a10;
            *reinterpret_cast<short8*>(&As[(arow0 + 64) * PAD + agg + 32]) = a11;
            *reinterpret_cast<short8*>(&Bs[arow0 * PAD + agg]) = b0;
            *reinterpret_cast<short8*>(&Bs[arow0 * PAD + agg + 32]) = b1;
        }
        __syncthreads();
#pragma unroll
        for (int kk = 0; kk < BKT / 32; ++kk) {
            short8 af[4], bf[2];
#pragma unroll
            for (int i = 0; i < 4; ++i)
                af[i] = *reinterpret_cast<const short8*>(
                    &As[(wr * 64 + i * 16 + fr) * PAD + kk * 32 + g * 8]);
#pragma unroll
            for (int j = 0; j < 2; ++j)
                bf[j] = *reinterpret_cast<const short8*>(
                    &Bs[(wc * 32 + j * 16 + fr) * PAD + kk * 32 + g * 8]);
#pragma unroll
            for (int i = 0; i < 4; ++i)
#pragma unroll
                for (int j = 0; j < 2; ++j)
                    acc[i][j] = __builtin_amdgcn_mfma_f32_16x16x32_bf16(
                        af[i], bf[j], acc[i][j], 0, 0, 0);
        }
        __syncthreads();
    }

#pragma unroll
    for (int i = 0; i < 4; ++i) {
#pragma unroll
        for (int j = 0; j < 2; ++j) {
#pragma unroll
            for (int r = 0; r < 4; ++r) {
                const int row = m0 + wr * 64 + i * 16 + g * 4 + r;
                const int col = n0 + wc * 32 + j * 16 + fr;
                if (GN && col >= N) continue;
                const float val = (acc[i][j][r] + (bias ? bias[col] : 0.f)) * oscale;
                if (epi == 0) {
                    ((float*)Cout)[(size_t)row * N + col] = val;
                } else if (epi == 1) {
                    const int b = row >> 10, l = row & 1023, hh = col >> 6, dh = col & 63;
                    ((unsigned short*)Cout)[(((size_t)(b * HH + hh)) * LL + l) * DH + dh] = f2b(val);
                } else if (epi == 2) {
                    const int b = row >> 10, l = row & 1023, hh = col >> 6, dh = col & 63;
                    ((unsigned short*)Cout)[(((size_t)(b * HH + hh)) * DH + dh) * LL + l] = f2b(val);
                } else {
                    ((unsigned short*)Cout)[(size_t)row * N + col] = f2b(val);
                }
            }
        }
    }
}

// Single-matrix GEMM (qpos table at BKT=64, final projection at BKT=32).
// ROUND 23: grid axes swapped (x = M-tile, y = N-tile) so A-panel-sharing
// blocks have ids congruent mod 8 -> same XCD L2 (the r22 trick that bought
// -19 us on gemm_qkv, applied to the remaining two GEMMs). gridX is a
// multiple of 8 in both uses, so id mod 8 == x mod 8 (constant per panel).
template <int EPI, bool GN, bool AF32, bool WF32, int BKT>
__global__ __launch_bounds__(256) void gemm_mfma(
    const void* __restrict__ A, const void* __restrict__ W,
    const float* __restrict__ bias, void* __restrict__ Cout,
    int M, int N, int K, float oscale)
{
    __shared__ alignas(16) unsigned short As[128 * (BKT + 8)];
    __shared__ alignas(16) unsigned short Bs[64 * (BKT + 8)];
    gemm_body<BKT, GN, AF32, WF32>(A, W, bias, Cout, M, N, K, oscale, EPI,
                                   blockIdx.x * 128, blockIdx.y * 64, As, Bs);
}

// ---------------------------------------------------------------------------
// 128 x 128 tile GEMM body (validated r19: 16 MFMA per 8 ds_read per K-step;
// viable because the z-merged launch gives 768 blocks = 3/CU co-resident).
// ---------------------------------------------------------------------------
template <bool AF32, bool WF32>
__device__ __forceinline__ void gemm_body128(
    const void* __restrict__ A, const void* __restrict__ W,
    const float* __restrict__ bias, void* __restrict__ Cout,
    int M, int N, int K, float oscale, int epi,
    int m0, int n0, unsigned short* As, unsigned short* Bs)
{
    const int tid = threadIdx.x;
    const int w = tid >> 6, lane = tid & 63;
    const int wr = w >> 1, wc = w & 1;
    const int g = lane >> 4, fr = lane & 15;

    f32x4 acc[4][4];
#pragma unroll
    for (int i = 0; i < 4; ++i)
#pragma unroll
        for (int j = 0; j < 4; ++j) acc[i][j] = (f32x4){0.f, 0.f, 0.f, 0.f};

    const int arow0 = tid >> 2, agg = (tid & 3) * 8;
    for (int k0 = 0; k0 < K; k0 += 32) {
        {
            short8 a0 = ld8<AF32>(A, (size_t)(m0 + arow0) * K + k0 + agg);
            short8 a1 = ld8<AF32>(A, (size_t)(m0 + arow0 + 64) * K + k0 + agg);
            short8 b0 = ld8<WF32>(W, (size_t)(n0 + arow0) * K + k0 + agg);
            short8 b1 = ld8<WF32>(W, (size_t)(n0 + arow0 + 64) * K + k0 + agg);
            *reinterpret_cast<short8*>(&As[arow0 * 40 + agg]) = a0;
            *reinterpret_cast<short8*>(&As[(arow0 + 64) * 40 + agg]) = a1;
            *reinterpret_cast<short8*>(&Bs[arow0 * 40 + agg]) = b0;
            *reinterpret_cast<short8*>(&Bs[(arow0 + 64) * 40 + agg]) = b1;
        }
        __syncthreads();
        short8 af[4], bf[4];
#pragma unroll
        for (int i = 0; i < 4; ++i)
            af[i] = *reinterpret_cast<const short8*>(
                &As[(wr * 64 + i * 16 + fr) * 40 + g * 8]);
#pragma unroll
        for (int j = 0; j < 4; ++j)
            bf[j] = *reinterpret_cast<const short8*>(
                &Bs[(wc * 64 + j * 16 + fr) * 40 + g * 8]);
#pragma unroll
        for (int i = 0; i < 4; ++i)
#pragma unroll
            for (int j = 0; j < 4; ++j)
                acc[i][j] = __builtin_amdgcn_mfma_f32_16x16x32_bf16(
                    af[i], bf[j], acc[i][j], 0, 0, 0);
        __syncthreads();
    }

#pragma unroll
    for (int i = 0; i < 4; ++i) {
#pragma unroll
        for (int j = 0; j < 4; ++j) {
#pragma unroll
            for (int r = 0; r < 4; ++r) {
                const int row = m0 + wr * 64 + i * 16 + g * 4 + r;
                const int col = n0 + wc * 64 + j * 16 + fr;
                const float val = (acc[i][j][r] + (bias ? bias[col] : 0.f)) * oscale;
                if (epi == 1) {
                    const int b = row >> 10, l = row & 1023, hh = col >> 6, dh = col & 63;
                    ((unsigned short*)Cout)[(((size_t)(b * HH + hh)) * LL + l) * DH + dh] = f2b(val);
                } else {
                    const int b = row >> 10, l = row & 1023, hh = col >> 6, dh = col & 63;
                    ((unsigned short*)Cout)[(((size_t)(b * HH + hh)) * DH + dh) * LL + l] = f2b(val);
                }
            }
        }
    }
}

// Merged Q/K/V projection, 128x128 tile (z selects matrix); 768 blocks.
// Grid (x = M-tile, y = N-tile): A-panel-sharing blocks on one XCD (r22).
__global__ __launch_bounds__(256) void gemm_qkv(
    const float* __restrict__ Q, const float* __restrict__ K,
    const float* __restrict__ V,
    const float* __restrict__ Wq, const float* __restrict__ Wk,
    const float* __restrict__ Wv,
    const float* __restrict__ bq, const float* __restrict__ bk,
    const float* __restrict__ bv,
    unsigned short* __restrict__ qbf, unsigned short* __restrict__ kbf,
    unsigned short* __restrict__ vT)
{
    __shared__ alignas(16) unsigned short As[128 * 40];
    __shared__ alignas(16) unsigned short Bs[128 * 40];
    const int z = blockIdx.z;
    const float* A = (z == 0) ? Q : (z == 1) ? K : V;
    const float* W = (z == 0) ? Wq : (z == 1) ? Wk : Wv;
    const float* bias = (z == 0) ? bq : (z == 1) ? bk : bv;
    void* Cout = (z == 0) ? (void*)qbf : (z == 1) ? (void*)kbf : (void*)vT;
    const int epi = (z == 2) ? 2 : 1;
    const float oscale = (z == 0) ? 0.125f : 1.0f;
    gemm_body128<true, true>(A, W, bias, Cout, BB * LL, DD, DD, oscale, epi,
                             blockIdx.x * 128, blockIdx.y * 128, As, Bs);
}

// ---------------------------------------------------------------------------
// MFMA attention — r14/r19 structure (135 us validated; setprio null r20,
// reverted). Split-K (2 q-groups x 2 k-halves, 8 tiles each), LDS qpos slab
// (19.3 KB, merge buffer aliased), bit-mask, banded gather, in-register
// online softmax, P via swizzled private LDS.
// ---------------------------------------------------------------------------
__global__ __launch_bounds__(256) void attn_mfma(
    const unsigned short* __restrict__ qbf,   // [bh][l][dh] bf16 (scaled 1/8)
    const unsigned short* __restrict__ kbf,   // [bh][l][dh] bf16
    const unsigned short* __restrict__ vT,    // [bh][dh][l] bf16
    const unsigned short* __restrict__ qpos,  // [bh*L][301] bf16 (scaled 1/8)
    const unsigned long long* __restrict__ mbits, // [b][q][L/64] bit-mask
    unsigned short* __restrict__ outb)        // [b][l][D] bf16
{
    const int bh = blockIdx.x;                // fast dim -> same-bh on one XCD
    const int qblk = blockIdx.y;
    const int b = bh >> 4, h = bh & 15;
    const int tid = threadIdx.x;
    const int w = tid >> 6;                   // 0..3
    const int qh = w & 1;                     // q-group
    const int kh = w >> 1;                    // k-half
    const int lane = tid & 63;
    const int g = lane >> 4;
    const int qc = lane & 15;
    const int gq = qblk * 32 + qh * 16 + qc;
    const int ql = qh * 16 + qc;              // local q row (0..31)

    __shared__ alignas(16) unsigned char Plds[4 * 2048];
    __shared__ alignas(16) unsigned short Qp[32 * NPOS];   // 19264 B; aliased
    float* Mrg = (float*)Qp;                  // as merge buf after 2nd barrier
    unsigned char* myP = Plds + w * 2048 + qc * 128;
    const int swz = (qc & 7) << 4;

    // ---- stage qpos slab (contiguous 32*301 bf16), coalesced ----
    {
        const unsigned short* qslab = qpos + ((size_t)bh * LL + (size_t)qblk * 32) * NPOS;
        for (int i = tid; i < (32 * NPOS) / 8; i += 256)
            *reinterpret_cast<short8*>(&Qp[i * 8]) =
                *reinterpret_cast<const short8*>(qslab + (size_t)i * 8);
    }

    const unsigned short* qrow = qbf + ((size_t)bh * LL + gq) * DH;
    const short8 qf0 = *reinterpret_cast<const short8*>(qrow + g * 8);
    const short8 qf1 = *reinterpret_cast<const short8*>(qrow + g * 8 + 32);

    const unsigned short* kb0 = kbf + (size_t)bh * LL * DH;
    const unsigned short* vb0 = vT + (size_t)bh * DH * LL;
    const unsigned long long* mwp = mbits + ((size_t)b * LL + gq) * (LL / 64);
    const unsigned short* qpr = &Qp[ql * NPOS];

    float mrun = -3.0e38f, lrun = 0.f;
    f32x4 o[4];
#pragma unroll
    for (int m = 0; m < 4; ++m) o[m] = (f32x4){0.f, 0.f, 0.f, 0.f};

    __syncthreads();                          // Qp ready (read-only in loop)
    const float c_left = b2f(qpr[300]);       // rel <= -150
    const float c_right = b2f(qpr[299]);      // rel >= +150

    // 8 tiles per wave, interleaved across k-halves
    for (int it = 0; it < 8; ++it) {
        const int kt = kh * 64 + it * 128;

        // ---- S^T = K . Q^T ----
        f32x4 s[4];
#pragma unroll
        for (int m = 0; m < 4; ++m) s[m] = (f32x4){0.f, 0.f, 0.f, 0.f};
#pragma unroll
        for (int m = 0; m < 4; ++m) {
            const unsigned short* krow = kb0 + (size_t)(kt + m * 16 + qc) * DH + g * 8;
            short8 a0 = *reinterpret_cast<const short8*>(krow);
            short8 a1 = *reinterpret_cast<const short8*>(krow + 32);
            s[m] = __builtin_amdgcn_mfma_f32_16x16x32_bf16(a0, qf0, s[m], 0, 0, 0);
            s[m] = __builtin_amdgcn_mfma_f32_16x16x32_bf16(a1, qf1, s[m], 0, 0, 0);
        }

        // ---- scores in place: banded qpos (LDS) + bit-mask ----
        const unsigned long long mw = mwp[kt >> 6];
        float tmax = -3.0e38f;
#pragma unroll
        for (int m = 0; m < 4; ++m) {
            const int kb = kt + m * 16 + g * 4;
            const unsigned msub = (unsigned)(mw >> (m * 16 + g * 4)) & 0xFu;
            const int p0 = kb - gq + 149;     // unclipped idx of r=0
            float rp0, rp1, rp2, rp3;
            if (p0 > 299) {                   // whole run right-saturated
                rp0 = rp1 = rp2 = rp3 = c_right;
            } else if (p0 < -3) {             // whole run left-saturated
                rp0 = rp1 = rp2 = rp3 = c_left;
            } else if (p0 >= 0 && p0 <= 296) { // strictly in band (LDS reads)
                rp0 = b2f(qpr[p0]);     rp1 = b2f(qpr[p0 + 1]);
                rp2 = b2f(qpr[p0 + 2]); rp3 = b2f(qpr[p0 + 3]);
            } else {                          // straddling band edge (rare)
                int i0 = p0 < 0 ? 300 : p0;
                int i1 = p0 + 1 < 0 ? 300 : (p0 + 1 > 299 ? 299 : p0 + 1);
                int i2 = p0 + 2 < 0 ? 300 : (p0 + 2 > 299 ? 299 : p0 + 2);
                int i3 = p0 + 3 > 299 ? 299 : p0 + 3;
                rp0 = b2f(qpr[i0]); rp1 = b2f(qpr[i1]);
                rp2 = b2f(qpr[i2]); rp3 = b2f(qpr[i3]);
            }
#pragma unroll
            for (int r = 0; r < 4; ++r) {
                const float rp = (r == 0 ? rp0 : r == 1 ? rp1 : r == 2 ? rp2 : rp3);
                float x = s[m][r] + rp;       // both pre-scaled by 1/8
                x = (msub >> r) & 1 ? NEG_INF : x;
                s[m][r] = x;
                tmax = fmaxf(tmax, x);
            }
        }

        // ---- online softmax (in-register, in-place exp) ----
        tmax = fmaxf(tmax, __shfl_xor(tmax, 16));
        tmax = fmaxf(tmax, __shfl_xor(tmax, 32));
        const float nm = fmaxf(mrun, tmax);
        const float al = __expf(mrun - nm);
        mrun = nm;
        float ls = 0.f;
#pragma unroll
        for (int m = 0; m < 4; ++m)
#pragma unroll
            for (int r = 0; r < 4; ++r) {
                const float p = __expf(s[m][r] - nm);
                s[m][r] = p;
                ls += p;
            }
        ls += __shfl_xor(ls, 16);
        ls += __shfl_xor(ls, 32);
        lrun = lrun * al + ls;
#pragma unroll
        for (int m = 0; m < 4; ++m) o[m] *= al;

        // ---- P -> bf16 -> private LDS (swizzled), re-read as B-frags ----
#pragma unroll
        for (int m = 0; m < 4; ++m) {
            *reinterpret_cast<unsigned*>(myP + ((32 * m + 8 * g) ^ swz)) = pack2(s[m][0], s[m][1]);
            *reinterpret_cast<unsigned*>(myP + ((32 * m + 8 * g + 4) ^ swz)) = pack2(s[m][2], s[m][3]);
        }
        const short8 pf0 = *reinterpret_cast<const short8*>(myP + ((16 * g) ^ swz));
        const short8 pf1 = *reinterpret_cast<const short8*>(myP + ((64 + 16 * g) ^ swz));

        // ---- O^T += V^T . P^T ----
#pragma unroll
        for (int m = 0; m < 4; ++m) {
            const unsigned short* vrow = vb0 + (size_t)(m * 16 + qc) * LL + kt + g * 8;
            short8 va0 = *reinterpret_cast<const short8*>(vrow);
            short8 va1 = *reinterpret_cast<const short8*>(vrow + 32);
            o[m] = __builtin_amdgcn_mfma_f32_16x16x32_bf16(va0, pf0, o[m], 0, 0, 0);
            o[m] = __builtin_amdgcn_mfma_f32_16x16x32_bf16(va1, pf1, o[m], 0, 0, 0);
        }
    }

    // ---- split-K merge (Mrg aliases Qp; barrier separates lifetimes) ----
    __syncthreads();                          // everyone done reading Qp
    if (kh == 1) {
        float* d = Mrg + ((size_t)qh * 64 + lane) * 18;
#pragma unroll
        for (int m = 0; m < 4; ++m)
#pragma unroll
            for (int r = 0; r < 4; ++r) d[m * 4 + r] = o[m][r];
        d[16] = mrun; d[17] = lrun;
    }
    __syncthreads();
    if (kh == 0) {
        const float* d = Mrg + ((size_t)qh * 64 + lane) * 18;
        const float m1 = d[16], l1 = d[17];
        const float M = fmaxf(mrun, m1);
        const float a0 = __expf(mrun - M), a1 = __expf(m1 - M);
        const float linv = 1.f / (lrun * a0 + l1 * a1);
        unsigned short* orow = outb + ((size_t)b * LL + gq) * DD + h * DH;
#pragma unroll
        for (int m = 0; m < 4; ++m) {
            ushort4 st;
            st.x = f2b((o[m][0] * a0 + d[m * 4 + 0] * a1) * linv);
            st.y = f2b((o[m][1] * a0 + d[m * 4 + 1] * a1) * linv);
            st.z = f2b((o[m][2] * a0 + d[m * 4 + 2] * a1) * linv);
            st.w = f2b((o[m][3] * a0 + d[m * 4 + 3] * a1) * linv);
            *reinterpret_cast<ushort4*>(orow + m * 16 + g * 4) = st;
        }
    }
}

// ---------------------------------------------------------------------------
// Inputs (dict order): 0 Q, 1 K, 2 V, 3 mask, 4 Wq, 5 bq, 6 Wk, 7 bk,
// 8 Wv, 9 bv, 10 Wo, 11 bo, 12 pos_emb.  Output: [B, L, D] float32.
// 5 dispatches. Workspace (bf16): qbf kbf vT attnb (4 x 4M) + qpos
// [65536][301] + mbits u64[65536] = ~72 MB.
// ---------------------------------------------------------------------------
extern "C" void kernel_launch(void* const* d_in, const int* in_sizes, int n_in,
                              void* d_out, int out_size, void* d_ws, size_t ws_size,
                              hipStream_t stream)
{
    const float* Q  = (const float*)d_in[0];
    const float* K  = (const float*)d_in[1];
    const float* V  = (const float*)d_in[2];
    const int* mask = (const int*)d_in[3];
    const float* Wq = (const float*)d_in[4];
    const float* bq = (const float*)d_in[5];
    const float* Wk = (const float*)d_in[6];
    const float* bk = (const float*)d_in[7];
    const float* Wv = (const float*)d_in[8];
    const float* bv = (const float*)d_in[9];
    const float* Wo = (const float*)d_in[10];
    const float* bo = (const float*)d_in[11];
    const float* pe = (const float*)d_in[12];
    float* out = (float*)d_out;

    unsigned short* ws = (unsigned short*)d_ws;
    const size_t NQ = (size_t)BB * HH * LL * DH;       // 4,194,304
    unsigned short* qbf = ws;
    unsigned short* kbf = qbf + NQ;
    unsigned short* vT  = kbf + NQ;
    unsigned short* attnb = vT + NQ;
    unsigned short* qpos = attnb + NQ;                 // bf16 [65536][301]
    unsigned long long* mbits =
        (unsigned long long*)(qpos + (size_t)BB * HH * LL * NPOS);

    const dim3 blk(256);
    const int M = BB * LL;                             // 4096

    pack_mask<<<dim3((BB * LL * LL / 64) * 64 / 256), blk, 0, stream>>>(mask, mbits);
    gemm_qkv<<<dim3(32, 8, 3), blk, 0, stream>>>(
        Q, K, V, Wq, Wk, Wv, bq, bk, bv, qbf, kbf, vT);
    gemm_mfma<3, true, false, true, 64><<<dim3(512, 5), blk, 0, stream>>>(
        qbf, pe, nullptr, qpos, BB * HH * LL, NPOS, DH, 1.0f);
    attn_mfma<<<dim3(BB * HH, LL / 32), dim3(256), 0, stream>>>(
        qbf, kbf, vT, qpos, mbits, attnb);
    gemm_mfma<0, false, false, true, 32><<<dim3(32, 16), blk, 0, stream>>>(
        attnb, Wo, bo, out, M, DD, DD, 1.0f);
}